// Round 6
// baseline (883.022 us; speedup 1.0000x reference)
//
#include <hip/hip_runtime.h>
#include <hip/hip_bf16.h>
#include <math.h>

#define BB 64
#define SS 64
#define VV 8
#define WW 256
#define DD 8
#define BS (BB*SS)        // 4096
#define BSV (BB*SS*VV)    // 32768

#define RB 392            // rowbuf stride (shorts)
#define HBs 1064          // hid stride
#define TB 264            // tmpb stride
#define AS 296            // crosskv A stride

typedef __attribute__((ext_vector_type(8))) short s8v;
typedef __attribute__((ext_vector_type(4))) float f4v;

__device__ __forceinline__ short f2b(float f) {
    __hip_bfloat16 h = __float2bfloat16(f);
    return *reinterpret_cast<short*>(&h);
}
__device__ __forceinline__ float b2f(short s) {
    __hip_bfloat16 h = *reinterpret_cast<__hip_bfloat16*>(&s);
    return __bfloat162float(h);
}

// ---------------------------------------------------------------------------
// B fragments are FRAGMENT-PACKED: bF[(k*64+lane)*8] -> one contiguous 1KB
// burst per wave per MFMA.
// rowgemm: generic (loads B inline), dual accumulator. rowgemm_pre: B
// pre-loaded (8 k-steps). rowgemm_preT<KS>: B pre-loaded, arbitrary K.
// rowgemm_mix: first 8 k-steps prefetched, remainder streamed.
// ---------------------------------------------------------------------------
__device__ __forceinline__ void bload8(const short* __restrict__ bF, int lane,
                                       s8v* __restrict__ dst)
{
#pragma unroll
    for (int k = 0; k < 8; k++)
        dst[k] = *(const s8v*)&bF[(size_t)(k * 64 + lane) * 8];
}

__device__ __forceinline__ f4v rowgemm(const short* __restrict__ aL, int lda,
                                       const short* __restrict__ bF,
                                       int ksteps, int lane)
{
    int lm = lane & 15, lq = lane >> 4;
    f4v a0 = (f4v){0.f, 0.f, 0.f, 0.f};
    f4v a1 = (f4v){0.f, 0.f, 0.f, 0.f};
    int k = 0;
#pragma unroll 8
    for (; k + 1 < ksteps; k += 2) {
        s8v x0 = *(const s8v*)&aL[lm * lda + k * 32 + lq * 8];
        s8v b0 = *(const s8v*)&bF[(size_t)(k * 64 + lane) * 8];
        s8v x1 = *(const s8v*)&aL[lm * lda + (k + 1) * 32 + lq * 8];
        s8v b1 = *(const s8v*)&bF[(size_t)((k + 1) * 64 + lane) * 8];
        a0 = __builtin_amdgcn_mfma_f32_16x16x32_bf16(x0, b0, a0, 0, 0, 0);
        a1 = __builtin_amdgcn_mfma_f32_16x16x32_bf16(x1, b1, a1, 0, 0, 0);
    }
    if (k < ksteps) {
        s8v x = *(const s8v*)&aL[lm * lda + k * 32 + lq * 8];
        s8v b = *(const s8v*)&bF[(size_t)(k * 64 + lane) * 8];
        a0 = __builtin_amdgcn_mfma_f32_16x16x32_bf16(x, b, a0, 0, 0, 0);
    }
    return a0 + a1;
}

__device__ __forceinline__ f4v rowgemm_pre(const short* __restrict__ aL, int lda,
                                           const s8v* __restrict__ bp, int lane)
{
    int lm = lane & 15, lq = lane >> 4;
    f4v a0 = (f4v){0.f, 0.f, 0.f, 0.f};
    f4v a1 = (f4v){0.f, 0.f, 0.f, 0.f};
#pragma unroll
    for (int k = 0; k < 8; k += 2) {
        s8v x0 = *(const s8v*)&aL[lm * lda + k * 32 + lq * 8];
        s8v x1 = *(const s8v*)&aL[lm * lda + (k + 1) * 32 + lq * 8];
        a0 = __builtin_amdgcn_mfma_f32_16x16x32_bf16(x0, bp[k], a0, 0, 0, 0);
        a1 = __builtin_amdgcn_mfma_f32_16x16x32_bf16(x1, bp[k + 1], a1, 0, 0, 0);
    }
    return a0 + a1;
}

template<int KS>
__device__ __forceinline__ f4v rowgemm_preT(const short* __restrict__ aL, int lda,
                                            const s8v* __restrict__ bp, int lane)
{
    int lm = lane & 15, lq = lane >> 4;
    f4v a0 = (f4v){0.f, 0.f, 0.f, 0.f};
    f4v a1 = (f4v){0.f, 0.f, 0.f, 0.f};
    int k = 0;
#pragma unroll
    for (; k + 1 < KS; k += 2) {
        s8v x0 = *(const s8v*)&aL[lm * lda + k * 32 + lq * 8];
        s8v x1 = *(const s8v*)&aL[lm * lda + (k + 1) * 32 + lq * 8];
        a0 = __builtin_amdgcn_mfma_f32_16x16x32_bf16(x0, bp[k], a0, 0, 0, 0);
        a1 = __builtin_amdgcn_mfma_f32_16x16x32_bf16(x1, bp[k + 1], a1, 0, 0, 0);
    }
    if (k < KS) {
        s8v x = *(const s8v*)&aL[lm * lda + k * 32 + lq * 8];
        a0 = __builtin_amdgcn_mfma_f32_16x16x32_bf16(x, bp[k], a0, 0, 0, 0);
    }
    return a0 + a1;
}

__device__ __forceinline__ f4v rowgemm_mix(const short* __restrict__ aL, int lda,
                                           const s8v* __restrict__ bp,
                                           const short* __restrict__ bF,
                                           int ksteps, int lane)
{
    int lm = lane & 15, lq = lane >> 4;
    f4v a0 = (f4v){0.f, 0.f, 0.f, 0.f};
    f4v a1 = (f4v){0.f, 0.f, 0.f, 0.f};
#pragma unroll
    for (int k = 0; k < 8; k += 2) {
        s8v x0 = *(const s8v*)&aL[lm * lda + k * 32 + lq * 8];
        s8v x1 = *(const s8v*)&aL[lm * lda + (k + 1) * 32 + lq * 8];
        a0 = __builtin_amdgcn_mfma_f32_16x16x32_bf16(x0, bp[k], a0, 0, 0, 0);
        a1 = __builtin_amdgcn_mfma_f32_16x16x32_bf16(x1, bp[k + 1], a1, 0, 0, 0);
    }
#pragma unroll 8
    for (int k = 8; k + 1 < ksteps; k += 2) {
        s8v x0 = *(const s8v*)&aL[lm * lda + k * 32 + lq * 8];
        s8v b0 = *(const s8v*)&bF[(size_t)(k * 64 + lane) * 8];
        s8v x1 = *(const s8v*)&aL[lm * lda + (k + 1) * 32 + lq * 8];
        s8v b1 = *(const s8v*)&bF[(size_t)((k + 1) * 64 + lane) * 8];
        a0 = __builtin_amdgcn_mfma_f32_16x16x32_bf16(x0, b0, a0, 0, 0, 0);
        a1 = __builtin_amdgcn_mfma_f32_16x16x32_bf16(x1, b1, a1, 0, 0, 0);
    }
    return a0 + a1;
}

// ---------------------------------------------------------------------------
// In-block LayerNorm of 16 rows x 256 cols held in registers v[t][r].
// Fused-moment version (var = E[x^2]-mean^2): 2 barriers instead of 4.
// 8-wave: each wave owns 2 column-tiles (32 cols). red = 256 floats.
// ---------------------------------------------------------------------------
__device__ __forceinline__ void ln_rows(
    float v[2][4], const float* __restrict__ g, const float* __restrict__ b,
    float eps, short* rowbuf, float* red, int w, int lm, int lq,
    short* __restrict__ outG, int row0)
{
    float ps[4], pq[4];
#pragma unroll
    for (int r = 0; r < 4; r++) {
        ps[r] = v[0][r] + v[1][r];
        pq[r] = v[0][r] * v[0][r] + v[1][r] * v[1][r];
    }
#pragma unroll
    for (int m = 1; m < 16; m <<= 1)
#pragma unroll
        for (int r = 0; r < 4; r++) {
            ps[r] += __shfl_xor(ps[r], m);
            pq[r] += __shfl_xor(pq[r], m);
        }
    if (lm == 0)
#pragma unroll
        for (int r = 0; r < 4; r++) {
            red[(lq * 4 + r) * 16 + w] = ps[r];
            red[(lq * 4 + r) * 16 + 8 + w] = pq[r];
        }
    __syncthreads();
    float mean[4], inv[4];
#pragma unroll
    for (int r = 0; r < 4; r++) {
        int row = lq * 4 + r;
        float s = 0.f, s2 = 0.f;
#pragma unroll
        for (int q = 0; q < 8; q++) { s += red[row * 16 + q]; s2 += red[row * 16 + 8 + q]; }
        mean[r] = s * (1.f / 256.f);
        float var = fmaxf(s2 * (1.f / 256.f) - mean[r] * mean[r], 0.f);
        inv[r] = rsqrtf(var + eps);
    }
#pragma unroll
    for (int t = 0; t < 2; t++) {
        int col = (w * 2 + t) * 16 + lm;
        float gc = g[col], bc = b[col];
#pragma unroll
        for (int r = 0; r < 4; r++) {
            float val = (v[t][r] - mean[r]) * inv[r] * gc + bc;
            rowbuf[(lq * 4 + r) * RB + col] = f2b(val);
            if (outG) outG[(size_t)(row0 + lq * 4 + r) * 256 + col] = f2b(val);
        }
    }
    __syncthreads();
}

// ---------------------------------------------------------------------------
// chainA: ow+res -> LN(c_fg) -> fw1 -> fw2+res -> [even: cat->q1->q2]
//         -> write fq -> LN(s_ln) -> sqkv.  Block = 16 rows, 512 thr, grid 256.
// B-fragment loads for each phase are prefetched into registers BEFORE the
// preceding barrier so the L2 latency hides under LN/staging barriers.
// ---------------------------------------------------------------------------
__global__ __launch_bounds__(512) void chainA(
    const short* __restrict__ obb, float* __restrict__ fq,
    const short* __restrict__ catb, short* __restrict__ qkv,
    const short* __restrict__ owT, const float* __restrict__ c_ob,
    const float* __restrict__ c_fg, const float* __restrict__ c_fb,
    const short* __restrict__ fw1T, const float* __restrict__ c_fb1,
    const short* __restrict__ fw2T, const float* __restrict__ c_fb2,
    const short* __restrict__ qw1T, const float* __restrict__ q_b1,
    const short* __restrict__ qw2T, const float* __restrict__ q_b2,
    const float* __restrict__ s_ln_g, const float* __restrict__ s_ln_b,
    const short* __restrict__ sqkvT, int even)
{
    __shared__ __align__(16) short rowbuf[16 * RB];
    __shared__ __align__(16) short hid[16 * HBs];
    __shared__ __align__(16) short tmpb[16 * TB];
    __shared__ float red[256];
    int tid = threadIdx.x, lane = tid & 63, w = tid >> 6;  // w in [0,8)
    int lm = lane & 15, lq = lane >> 4;
    int row0 = blockIdx.x * 16;
    // prefetch ow B-fragments (overlaps obb staging + barrier)
    s8v bo[16];
    bload8(owT + (size_t)(w * 2 + 0) * 4096, lane, bo);
    bload8(owT + (size_t)(w * 2 + 1) * 4096, lane, bo + 8);
    {
        int r = tid >> 5, c = (tid & 31) * 8;
        *(s8v*)&rowbuf[r * RB + c] = *(const s8v*)&obb[(size_t)(row0 + r) * 256 + c];
    }
    __syncthreads();
    float fqreg[2][4];
#pragma unroll
    for (int t = 0; t < 2; t++) {
        f4v o = rowgemm_pre(rowbuf, RB, bo + t * 8, lane);
        int col = (w * 2 + t) * 16 + lm;
        float bb = c_ob[col];
#pragma unroll
        for (int r = 0; r < 4; r++)
            fqreg[t][r] = o[r] + bb + fq[(size_t)(row0 + lq * 4 + r) * 256 + col];
    }
    // prefetch fw1 tiles 0..3 (overlaps the LN barriers)
    s8v bf[32];
    bload8(fw1T + (size_t)(w * 8 + 0) * 4096, lane, bf);
    bload8(fw1T + (size_t)(w * 8 + 1) * 4096, lane, bf + 8);
    bload8(fw1T + (size_t)(w * 8 + 2) * 4096, lane, bf + 16);
    bload8(fw1T + (size_t)(w * 8 + 3) * 4096, lane, bf + 24);
    ln_rows(fqreg, c_fg, c_fb, 1e-6f, rowbuf, red, w, lm, lq, nullptr, row0);
#pragma unroll
    for (int t = 0; t < 8; t++) {
        f4v o = (t < 4) ? rowgemm_pre(rowbuf, RB, bf + t * 8, lane)
                        : rowgemm(rowbuf, RB, fw1T + (size_t)(w * 8 + t) * 4096, 8, lane);
        int col = (w * 8 + t) * 16 + lm;
        float bb = c_fb1[col];
#pragma unroll
        for (int r = 0; r < 4; r++)
            hid[(lq * 4 + r) * HBs + col] = f2b(fmaxf(o[r] + bb, 0.f));
    }
    // prefetch fw2 first 8 k-steps of both tiles (overlaps hid barrier)
    s8v b2[16];
    bload8(fw2T + (size_t)(w * 2 + 0) * 16384, lane, b2);
    bload8(fw2T + (size_t)(w * 2 + 1) * 16384, lane, b2 + 8);
    __syncthreads();
#pragma unroll
    for (int t = 0; t < 2; t++) {
        f4v o = rowgemm_mix(hid, HBs, b2 + t * 8,
                            fw2T + (size_t)(w * 2 + t) * 16384, 32, lane);
        int col = (w * 2 + t) * 16 + lm;
        float bb = c_fb2[col];
#pragma unroll
        for (int r = 0; r < 4; r++)
            fqreg[t][r] = o[r] + bb + fqreg[t][r];
    }
    if (even) {
#pragma unroll
        for (int t = 0; t < 2; t++) {
            int col = (w * 2 + t) * 16 + lm;
#pragma unroll
            for (int r = 0; r < 4; r++)
                rowbuf[(lq * 4 + r) * RB + col] = f2b(fqreg[t][r]);
        }
        if (tid < 256) {
            int r = tid >> 4, c = (tid & 15) * 8;
            *(s8v*)&rowbuf[r * RB + 256 + c] = *(const s8v*)&catb[(size_t)(row0 + r) * 384 + 256 + c];
        }
        // prefetch q1 first 8 k-steps of both tiles (overlaps barrier)
        s8v bq[16];
        bload8(qw1T + (size_t)(w * 2 + 0) * 6144, lane, bq);
        bload8(qw1T + (size_t)(w * 2 + 1) * 6144, lane, bq + 8);
        __syncthreads();
#pragma unroll
        for (int t = 0; t < 2; t++) {
            f4v o = rowgemm_mix(rowbuf, RB, bq + t * 8,
                                qw1T + (size_t)(w * 2 + t) * 6144, 12, lane);
            int col = (w * 2 + t) * 16 + lm;
            float bb = q_b1[col];
#pragma unroll
            for (int r = 0; r < 4; r++)
                tmpb[(lq * 4 + r) * TB + col] = f2b(fmaxf(o[r] + bb, 0.f));
        }
        // prefetch q2 (full, both tiles) across the tmpb barrier
        s8v bq2[16];
        bload8(qw2T + (size_t)(w * 2 + 0) * 4096, lane, bq2);
        bload8(qw2T + (size_t)(w * 2 + 1) * 4096, lane, bq2 + 8);
        __syncthreads();
#pragma unroll
        for (int t = 0; t < 2; t++) {
            f4v o = rowgemm_pre(tmpb, TB, bq2 + t * 8, lane);
            int col = (w * 2 + t) * 16 + lm;
            float bb = q_b2[col];
#pragma unroll
            for (int r = 0; r < 4; r++)
                fqreg[t][r] = o[r] + bb;
        }
    }
#pragma unroll
    for (int t = 0; t < 2; t++) {
        int col = (w * 2 + t) * 16 + lm;
#pragma unroll
        for (int r = 0; r < 4; r++)
            fq[(size_t)(row0 + lq * 4 + r) * 256 + col] = fqreg[t][r];
    }
    // prefetch sqkv tiles 0..2 (overlaps the LN barriers)
    s8v bs[24];
    bload8(sqkvT + (size_t)(w * 6 + 0) * 4096, lane, bs);
    bload8(sqkvT + (size_t)(w * 6 + 1) * 4096, lane, bs + 8);
    bload8(sqkvT + (size_t)(w * 6 + 2) * 4096, lane, bs + 16);
    ln_rows(fqreg, s_ln_g, s_ln_b, 1e-6f, rowbuf, red, w, lm, lq, nullptr, row0);
#pragma unroll
    for (int t = 0; t < 6; t++) {
        f4v o = (t < 3) ? rowgemm_pre(rowbuf, RB, bs + t * 8, lane)
                        : rowgemm(rowbuf, RB, sqkvT + (size_t)(w * 6 + t) * 4096, 8, lane);
        int col = (w * 6 + t) * 16 + lm;
#pragma unroll
        for (int r = 0; r < 4; r++)
            qkv[(size_t)(row0 + lq * 4 + r) * 768 + col] = f2b(o[r]);
    }
}

// ---------------------------------------------------------------------------
// chainB (attention-fused): self-attn (QK^T+softmax+PV for this block's 16
// rows, all 4 heads, K/V of its batch) -> rowbuf -> sow+res -> LN(s_fg) ->
// sfw1 -> sfw2+res -> write fq -> LN(next c_ln | final norm[->hb]) ->
// qw_next -> qf.  512 threads, grid 256.
// ---------------------------------------------------------------------------
__global__ __launch_bounds__(512) void chainB(
    const short* __restrict__ qkv, float* __restrict__ fq,
    const short* __restrict__ sowT, const float* __restrict__ s_ob,
    const float* __restrict__ s_fg, const float* __restrict__ s_fb,
    const short* __restrict__ sfw1T, const float* __restrict__ s_fb1,
    const short* __restrict__ sfw2T, const float* __restrict__ s_fb2,
    const float* __restrict__ ln2_g, const float* __restrict__ ln2_b, float eps2,
    const short* __restrict__ qwTn, float* __restrict__ qf,
    short* __restrict__ hbG)
{
    __shared__ __align__(16) short rowbuf[16 * RB];
    __shared__ __align__(16) short hid[16 * HBs];
    __shared__ __align__(16) short vt[4][64 * 72];
    __shared__ __align__(16) short pbuf[4][16 * 72];
    __shared__ float red[256];
    int tid = threadIdx.x, lane = tid & 63, w = tid >> 6;
    int lm = lane & 15, lq = lane >> 4;
    int row0 = blockIdx.x * 16;
    int b = row0 >> 6;
    const short* qb = qkv + (size_t)b * 64 * 768;
    // stage V^T for all 4 heads: tid -> (h, row, col-half)
    {
        int h = tid >> 7, t2 = tid & 127, row = t2 >> 1, c0 = (t2 & 1) * 4;
        const short* vrow = qb + (size_t)row * 768 + 512 + h * 64;
#pragma unroll
        for (int c = c0; c < c0 + 4; c++) {
            s8v v = *(const s8v*)&vrow[c * 8];
#pragma unroll
            for (int j = 0; j < 8; j++)
                vt[h][(c * 8 + j) * 72 + row] = v[j];
        }
    }
    // prefetch sow B fragments (all waves; hides under attention phase)
    s8v bo[16];
    bload8(sowT + (size_t)(w * 2 + 0) * 4096, lane, bo);
    bload8(sowT + (size_t)(w * 2 + 1) * 4096, lane, bo + 8);
    // waves 0-3: QK^T + softmax -> pbuf[h]  (head h = w)
    if (w < 4) {
        int h = w;
        s8v qfr[2], kf[4][2];
#pragma unroll
        for (int c = 0; c < 2; c++) {
            qfr[c] = *(const s8v*)&qkv[(size_t)(row0 + lm) * 768 + h * 64 + c * 32 + lq * 8];
#pragma unroll
            for (int j = 0; j < 4; j++)
                kf[j][c] = *(const s8v*)&qb[(size_t)(j * 16 + lm) * 768 + 256 + h * 64 + c * 32 + lq * 8];
        }
        f4v acc[4];
#pragma unroll
        for (int j = 0; j < 4; j++) acc[j] = (f4v){0.f, 0.f, 0.f, 0.f};
#pragma unroll
        for (int c = 0; c < 2; c++)
#pragma unroll
            for (int j = 0; j < 4; j++)
                acc[j] = __builtin_amdgcn_mfma_f32_16x16x32_bf16(qfr[c], kf[j][c], acc[j], 0, 0, 0);
#pragma unroll
        for (int r = 0; r < 4; r++) {
            float lv[4];
#pragma unroll
            for (int j = 0; j < 4; j++) lv[j] = acc[j][r] * 0.125f;
            float mx = fmaxf(fmaxf(lv[0], lv[1]), fmaxf(lv[2], lv[3]));
            for (int d = 1; d < 16; d <<= 1) mx = fmaxf(mx, __shfl_xor(mx, d));
            float sum = 0.f;
#pragma unroll
            for (int j = 0; j < 4; j++) { lv[j] = expf(lv[j] - mx); sum += lv[j]; }
            for (int d = 1; d < 16; d <<= 1) sum += __shfl_xor(sum, d);
            float inv = 1.f / sum;
            int row = lq * 4 + r;
#pragma unroll
            for (int j = 0; j < 4; j++)
                pbuf[h][row * 72 + j * 16 + lm] = f2b(lv[j] * inv);
        }
    }
    __syncthreads();
    // all 8 waves: PV for (h = w>>1, half = w&1) -> rowbuf cols h*64+half*32..
    {
        int h = w >> 1, half = w & 1;
        s8v af[2], bv[2][2];
#pragma unroll
        for (int c = 0; c < 2; c++) {
            af[c] = *(const s8v*)&pbuf[h][lm * 72 + c * 32 + lq * 8];
#pragma unroll
            for (int nt = 0; nt < 2; nt++)
                bv[nt][c] = *(const s8v*)&vt[h][((half * 2 + nt) * 16 + lm) * 72 + c * 32 + lq * 8];
        }
        f4v o2[2];
        o2[0] = (f4v){0.f, 0.f, 0.f, 0.f};
        o2[1] = (f4v){0.f, 0.f, 0.f, 0.f};
#pragma unroll
        for (int c = 0; c < 2; c++)
#pragma unroll
            for (int nt = 0; nt < 2; nt++)
                o2[nt] = __builtin_amdgcn_mfma_f32_16x16x32_bf16(af[c], bv[nt][c], o2[nt], 0, 0, 0);
#pragma unroll
        for (int nt = 0; nt < 2; nt++) {
            int col = h * 64 + (half * 2 + nt) * 16 + lm;
#pragma unroll
            for (int r = 0; r < 4; r++)
                rowbuf[(lq * 4 + r) * RB + col] = f2b(o2[nt][r]);
        }
    }
    __syncthreads();
    float fqreg[2][4];
#pragma unroll
    for (int t = 0; t < 2; t++) {
        f4v o = rowgemm_pre(rowbuf, RB, bo + t * 8, lane);
        int col = (w * 2 + t) * 16 + lm;
        float bb = s_ob[col];
#pragma unroll
        for (int r = 0; r < 4; r++)
            fqreg[t][r] = o[r] + bb + fq[(size_t)(row0 + lq * 4 + r) * 256 + col];
    }
    s8v bf[32];
    bload8(sfw1T + (size_t)(w * 8 + 0) * 4096, lane, bf);
    bload8(sfw1T + (size_t)(w * 8 + 1) * 4096, lane, bf + 8);
    bload8(sfw1T + (size_t)(w * 8 + 2) * 4096, lane, bf + 16);
    bload8(sfw1T + (size_t)(w * 8 + 3) * 4096, lane, bf + 24);
    ln_rows(fqreg, s_fg, s_fb, 1e-6f, rowbuf, red, w, lm, lq, nullptr, row0);
#pragma unroll
    for (int t = 0; t < 8; t++) {
        f4v o = (t < 4) ? rowgemm_pre(rowbuf, RB, bf + t * 8, lane)
                        : rowgemm(rowbuf, RB, sfw1T + (size_t)(w * 8 + t) * 4096, 8, lane);
        int col = (w * 8 + t) * 16 + lm;
        float bb = s_fb1[col];
#pragma unroll
        for (int r = 0; r < 4; r++)
            hid[(lq * 4 + r) * HBs + col] = f2b(fmaxf(o[r] + bb, 0.f));
    }
    s8v b2[16];
    bload8(sfw2T + (size_t)(w * 2 + 0) * 16384, lane, b2);
    bload8(sfw2T + (size_t)(w * 2 + 1) * 16384, lane, b2 + 8);
    __syncthreads();
#pragma unroll
    for (int t = 0; t < 2; t++) {
        f4v o = rowgemm_mix(hid, HBs, b2 + t * 8,
                            sfw2T + (size_t)(w * 2 + t) * 16384, 32, lane);
        int col = (w * 2 + t) * 16 + lm;
        float bb = s_fb2[col];
#pragma unroll
        for (int r = 0; r < 4; r++)
            fqreg[t][r] = o[r] + bb + fqreg[t][r];
    }
#pragma unroll
    for (int t = 0; t < 2; t++) {
        int col = (w * 2 + t) * 16 + lm;
#pragma unroll
        for (int r = 0; r < 4; r++)
            fq[(size_t)(row0 + lq * 4 + r) * 256 + col] = fqreg[t][r];
    }
    s8v bq[16];
    if (qwTn) {
        bload8(qwTn + (size_t)(w * 2 + 0) * 4096, lane, bq);
        bload8(qwTn + (size_t)(w * 2 + 1) * 4096, lane, bq + 8);
    }
    ln_rows(fqreg, ln2_g, ln2_b, eps2, rowbuf, red, w, lm, lq, hbG, row0);
    if (qwTn) {
#pragma unroll
        for (int t = 0; t < 2; t++) {
            f4v o = rowgemm_pre(rowbuf, RB, bq + t * 8, lane);
            int col = (w * 2 + t) * 16 + lm;
#pragma unroll
            for (int r = 0; r < 4; r++)
                qf[(size_t)(row0 + lq * 4 + r) * 256 + col] = o[r];
        }
    }
}

// layer-0 q projection: qf = xq @ qw0 (frag-packed), block = 16 rows
__global__ __launch_bounds__(256) void qgemm0(
    const short* __restrict__ xq, const short* __restrict__ qwT0,
    float* __restrict__ qf)
{
    __shared__ __align__(16) short rowbuf[16 * TB];
    int tid = threadIdx.x, lane = tid & 63, w = tid >> 6;
    int lm = lane & 15, lq = lane >> 4;
    int row0 = blockIdx.x * 16;
    {
        int r = tid >> 4, c = (tid & 15) * 16;
        *(s8v*)&rowbuf[r * TB + c]     = *(const s8v*)&xq[(size_t)(row0 + r) * 256 + c];
        *(s8v*)&rowbuf[r * TB + c + 8] = *(const s8v*)&xq[(size_t)(row0 + r) * 256 + c + 8];
    }
    __syncthreads();
#pragma unroll
    for (int t = 0; t < 4; t++) {
        f4v o = rowgemm(rowbuf, TB, qwT0 + (size_t)(w * 4 + t) * 4096, 8, lane);
        int col = (w * 4 + t) * 16 + lm;
#pragma unroll
        for (int r = 0; r < 4; r++)
            qf[(size_t)(row0 + lq * 4 + r) * 256 + col] = o[r];
    }
}

// ---------------------------------------------------------------------------
// crosskv: fused kv-projection + cross-attention. Block = 32 kv rows
// (4 samples), grid 1024. B fragments hoisted across the two row-tiles
// (halves kvp L2 traffic) and prefetched across phase barriers.
// ---------------------------------------------------------------------------
__global__ __launch_bounds__(256) void crosskv(
    const short* __restrict__ rgbf, const short* __restrict__ hall_l,
    const short* __restrict__ kvpT_l, const float* __restrict__ qf,
    const int* __restrict__ mask,
    const short* __restrict__ aw1T_l, const float* __restrict__ ab1,
    const short* __restrict__ aw2T_l, const float* __restrict__ ab2,
    short* __restrict__ obb)
{
    __shared__ __align__(16) short A_s[32 * AS];
    __shared__ __align__(16) short a_s[32 * 264];
    __shared__ __align__(16) short ph_s[32 * 40];
    __shared__ int msk[32];
    int blk = blockIdx.x, tid = threadIdx.x;
    int row0 = blk * 32, bs0 = blk * 4;
    int lane = tid & 63, w = tid >> 6, lm = lane & 15, lq = lane >> 4;
    if (tid < 32) msk[tid] = mask[bs0 * 8 + tid];
    // prefetch first k-proj ntile's B (hides under A staging + barrier)
    s8v bk0[9];
#pragma unroll
    for (int k = 0; k < 9; k++)
        bk0[k] = *(const s8v*)&kvpT_l[((size_t)(w * 4) * 9 + k) * 512 + lane * 8];
#pragma unroll
    for (int i = 0; i < 4; i++) {
        int e = tid + i * 256;
        int r = e >> 5, c = (e & 31) << 3;
        *(s8v*)&A_s[r * AS + c] = *(const s8v*)&rgbf[(size_t)(row0 + r) * 256 + c];
    }
    if (tid < 128) {
        int r = tid >> 2, c = (tid & 3) << 3;
        *(s8v*)&A_s[r * AS + 256 + c] = *(const s8v*)&hall_l[(size_t)(row0 + r) * 32 + c];
    }
    __syncthreads();
    // k-half: B loaded once per ntile, reused for both row-tiles
#pragma unroll
    for (int j4 = 0; j4 < 4; j4++) {
        int nt = w * 4 + j4;
        s8v bk[9];
#pragma unroll
        for (int k = 0; k < 9; k++)
            bk[k] = j4 ? *(const s8v*)&kvpT_l[((size_t)nt * 9 + k) * 512 + lane * 8]
                       : bk0[k];
#pragma unroll
        for (int i = 0; i < 2; i++) {
            f4v acc = rowgemm_preT<9>(&A_s[i * 16 * AS], AS, bk, lane);
#pragma unroll
            for (int r = 0; r < 4; r++) {
                int row = i * 16 + lq * 4 + r, col = nt * 16 + lm;
                float q = qf[(size_t)(bs0 + (row >> 3)) * 256 + col];
                a_s[row * 264 + col] = f2b(acc[r] - q);
            }
        }
    }
    // prefetch aw1 B (hides under the barrier)
    s8v baw[8];
    bload8(aw1T_l + (size_t)(w & 1) * 4096, lane, baw);
    __syncthreads();
    // ph = relu(a_in @ aw1 + ab1)
    {
        int i = w >> 1, j = w & 1;
        f4v acc = rowgemm_pre(&a_s[i * 16 * 264], 264, baw, lane);
        int col = j * 16 + lm;
        float bb = ab1[col];
#pragma unroll
        for (int r = 0; r < 4; r++)
            ph_s[(i * 16 + lq * 4 + r) * 40 + col] = f2b(fmaxf(acc[r] + bb, 0.f));
    }
    // prefetch aw2 (K=1, 4 tiles) and first v-proj ntile's B
    s8v baw2[4];
#pragma unroll
    for (int j4 = 0; j4 < 4; j4++)
        baw2[j4] = *(const s8v*)&aw2T_l[(size_t)(w * 4 + j4) * 512 + lane * 8];
    s8v bv0[9];
#pragma unroll
    for (int k = 0; k < 9; k++)
        bv0[k] = *(const s8v*)&kvpT_l[((size_t)(16 + w * 4) * 9 + k) * 512 + lane * 8];
    __syncthreads();
    // a3 = ph @ aw2 (single k-step; A-fragment hoisted across the 4 tiles)
    f4v a3[2][4];
#pragma unroll
    for (int i = 0; i < 2; i++) {
        s8v pa = *(const s8v*)&ph_s[(i * 16 + lm) * 40 + lq * 8];
#pragma unroll
        for (int j4 = 0; j4 < 4; j4++)
            a3[i][j4] = __builtin_amdgcn_mfma_f32_16x16x32_bf16(
                pa, baw2[j4], (f4v){0.f, 0.f, 0.f, 0.f}, 0, 0, 0);
    }
    // v-half: B loaded once per ntile, reused for both row-tiles
#pragma unroll
    for (int j4 = 0; j4 < 4; j4++) {
        int nt = w * 4 + j4;
        s8v bv[9];
#pragma unroll
        for (int k = 0; k < 9; k++)
            bv[k] = j4 ? *(const s8v*)&kvpT_l[((size_t)(16 + nt) * 9 + k) * 512 + lane * 8]
                       : bv0[k];
#pragma unroll
        for (int i = 0; i < 2; i++) {
            f4v acc = rowgemm_preT<9>(&A_s[i * 16 * AS], AS, bv, lane);
#pragma unroll
            for (int r = 0; r < 4; r++)
                a_s[(i * 16 + lq * 4 + r) * 264 + nt * 16 + lm] = f2b(acc[r]);
        }
    }
    __syncthreads();
    // masked softmax over views + weighted sum
#pragma unroll
    for (int i = 0; i < 2; i++) {
        int sample = i * 2 + (lq >> 1);
        int mk[4];
#pragma unroll
        for (int r = 0; r < 4; r++) mk[r] = msk[sample * 8 + (lq & 1) * 4 + r];
#pragma unroll
        for (int j4 = 0; j4 < 4; j4++) {
            int col = (w * 4 + j4) * 16 + lm;
            float bv = ab2[col];
            float vals[4];
#pragma unroll
            for (int r = 0; r < 4; r++) vals[r] = mk[r] ? (a3[i][j4][r] + bv) : -1e9f;
            float mx = fmaxf(fmaxf(vals[0], vals[1]), fmaxf(vals[2], vals[3]));
            mx = fmaxf(mx, __shfl_xor(mx, 16));
            float ev[4], s = 0.f;
#pragma unroll
            for (int r = 0; r < 4; r++) { ev[r] = expf(vals[r] - mx); s += ev[r]; }
            s += __shfl_xor(s, 16);
            float o = 0.f;
#pragma unroll
            for (int r = 0; r < 4; r++)
                o += ev[r] * b2f(a_s[(i * 16 + lq * 4 + r) * 264 + col]);
            o += __shfl_xor(o, 16);
            o /= s;
            if (!(lq & 1)) obb[(size_t)(bs0 + sample) * 256 + col] = f2b(o);
        }
    }
}

// ---------------------------------------------------------------------------
// bf16 MFMA GEMM (BK=32, LDS stride 40) — preamble only (row-major B^T).
// ---------------------------------------------------------------------------
template<int TM, int TN, int WM, int WN, bool OUTBF>
__global__ __launch_bounds__(256) void gemm_mfma(
    const short* __restrict__ A, const short* __restrict__ Bt,
    const float* __restrict__ bias, const float* __restrict__ res,
    float* __restrict__ Cf, short* __restrict__ Cb,
    int M, int N, int K, int ldc, int relu)
{
    constexpr int MT  = WM / 16;
    constexpr int NT  = WN / 16;
    constexpr int RWN = TN / WN;
    __shared__ __align__(16) short As[TM * 40];
    __shared__ __align__(16) short Bs[TN * 40];
    int tid = threadIdx.x;
    int m0 = blockIdx.y * TM, n0 = blockIdx.x * TN;
    int lane = tid & 63, w = tid >> 6;
    int lm = lane & 15, lq = lane >> 4;
    int wm = (w / RWN) * WM, wn = (w % RWN) * WN;
    f4v acc[MT][NT];
#pragma unroll
    for (int i = 0; i < MT; i++)
#pragma unroll
        for (int j = 0; j < NT; j++) acc[i][j] = (f4v){0.f, 0.f, 0.f, 0.f};

    for (int k0 = 0; k0 < K; k0 += 32) {
        for (int c = tid; c < TM * 4; c += 256) {
            int r = c >> 2, kc = (c & 3) << 3;
            *(s8v*)&As[r * 40 + kc] = *(const s8v*)&A[(size_t)(m0 + r) * K + k0 + kc];
        }
        for (int c = tid; c < TN * 4; c += 256) {
            int r = c >> 2, kc = (c & 3) << 3;
            *(s8v*)&Bs[r * 40 + kc] = *(const s8v*)&Bt[(size_t)(n0 + r) * K + k0 + kc];
        }
        __syncthreads();
        s8v af[MT], bfv[NT];
#pragma unroll
        for (int i = 0; i < MT; i++)
            af[i] = *(const s8v*)&As[(wm + i * 16 + lm) * 40 + lq * 8];
#pragma unroll
        for (int j = 0; j < NT; j++)
            bfv[j] = *(const s8v*)&Bs[(wn + j * 16 + lm) * 40 + lq * 8];
#pragma unroll
        for (int i = 0; i < MT; i++)
#pragma unroll
            for (int j = 0; j < NT; j++)
                acc[i][j] = __builtin_amdgcn_mfma_f32_16x16x32_bf16(af[i], bfv[j], acc[i][j], 0, 0, 0);
        __syncthreads();
    }
#pragma unroll
    for (int i = 0; i < MT; i++) {
        int row = m0 + wm + i * 16 + lq * 4;
#pragma unroll
        for (int j = 0; j < NT; j++) {
            int col = n0 + wn + j * 16 + lm;
            float bv = bias ? bias[col] : 0.f;
#pragma unroll
            for (int r = 0; r < 4; r++) {
                float v = acc[i][j][r] + bv;
                if (relu) v = fmaxf(v, 0.f);
                size_t idx = (size_t)(row + r) * ldc + col;
                if (OUTBF) {
                    Cb[idx] = f2b(v);
                } else {
                    if (res) v += res[idx];
                    Cf[idx] = v;
                }
            }
        }
    }
}

// ---------------------------------------------------------------------------
// Batched weight convert: fp32 [K,N] -> bf16, either row-major [N,Kpad]
// (frag=0) or MFMA-fragment-packed [ntile][kstep][lane][8] (frag=1).
// ---------------------------------------------------------------------------
struct WJob {
    const float* src; short* dst;
    int K, N, KS, ntoff, ksoff, Kpad, zi, gy, nblk, frag;
    size_t zo;
};
struct WJobs { WJob j[20]; };

__global__ void wconv_all(WJobs jobs)
{
    __shared__ float t[32][33];
    int b = blockIdx.x, ji = 0;
    while (b >= jobs.j[ji].nblk) { b -= jobs.j[ji].nblk; ji++; }
    WJob J = jobs.j[ji];
    int gx = J.N >> 5;
    int z = b / (gx * J.gy);
    int rem = b - z * (gx * J.gy);
    int by = rem / gx, bx = rem - by * gx;
    const float* W = J.src + (size_t)z * J.zi;
    short* Wt = J.dst + (size_t)z * J.zo;
    int n0 = bx * 32, k0 = by * 32;
    int tx = threadIdx.x, ty = threadIdx.y;
#pragma unroll
    for (int i = 0; i < 4; i++) {
        int k = k0 + ty + i * 8;
        t[ty + i * 8][tx] = (k < J.K) ? W[(size_t)k * J.N + n0 + tx] : 0.f;
    }
    __syncthreads();
    if (J.frag) {
        if (ty < 4) {
            int n = n0 + tx;
            int nt = J.ntoff + (n >> 4), lmm = n & 15;
            int ks = J.ksoff + (k0 >> 5);
            s8v o;
#pragma unroll
            for (int jj = 0; jj < 8; jj++) o[jj] = f2b(t[ty * 8 + jj][tx]);
            *(s8v*)&Wt[(((size_t)nt * J.KS + ks) * 64 + ty * 16 + lmm) * 8] = o;
        }
    } else {
#pragma unroll
        for (int i = 0; i < 4; i++) {
            int n = n0 + ty + i * 8;
            Wt[(size_t)n * J.Kpad + k0 + tx] = f2b(t[tx][ty + i * 8]);
        }
    }
}

// catb tail computed directly from pts/ray_d (penc inline)
__global__ void catpenc(const float* __restrict__ pts, const float* __restrict__ ray_d,
                        short* __restrict__ catb)
{
    int idx = blockIdx.x * 256 + threadIdx.x;
    int bs = idx >> 7, c = idx & 127;
    float v = 0.f;
    if (c < 63) {
        if (c < 3) v = pts[bs * 3 + c];
        else {
            int e = c - 3; int d, k; bool sn;
            if (e < 30) { d = e / 10; k = e - d * 10; sn = true; }
            else { e -= 30; d = e / 10; k = e - d * 10; sn = false; }
            float ang = pts[bs * 3 + d] * (float)(1 << k);
            v = sn ? sinf(ang) : cosf(ang);
        }
    } else if (c < 90) {
        int e = c - 63, b = bs >> 6;
        float x = ray_d[b * 3], y = ray_d[b * 3 + 1], z = ray_d[b * 3 + 2];
        float inv = rsqrtf(x * x + y * y + z * z);
        float vv[3] = {x * inv, y * inv, z * inv};
        if (e < 3) v = vv[e];
        else if (e < 15) { int d = (e - 3) >> 2, k = (e - 3) & 3; v = sinf(vv[d] * (float)(1 << k)); }
        else { int d = (e - 15) >> 2, k = (e - 15) & 3; v = cosf(vv[d] * (float)(1 << k)); }
    }
    catb[(size_t)bs * 384 + 256 + c] = f2b(v);
}

// rgb_feat pad-convert + hall (all 8 layers) in one launch
__global__ void rgbhall(const float* __restrict__ rgb_feat, const float* __restrict__ rdiff,
                        const float* __restrict__ pw1, const float* __restrict__ pb1,
                        short* __restrict__ rgbp, short* __restrict__ hall)
{
    int idx = blockIdx.x * 256 + threadIdx.x;
    if (idx < BSV * 64) {
        int row = idx >> 6, col = idx & 63;
        rgbp[idx] = f2b(col < 35 ? rgb_feat[row * 35 + col] : 0.f);
    } else {
        int k = idx - BSV * 64;
        int t = k & 31, row = (k >> 5) & (BSV - 1), l = k >> 20;
        float a = pb1[l * 32 + t];
        for (int c = 0; c < 4; c++) a += rdiff[row * 4 + c] * pw1[l * 128 + c * 32 + t];
        hall[k] = f2b(fmaxf(a, 0.f));
    }
}

// view-max + layer-0 LayerNorm fused
__global__ __launch_bounds__(256) void vmaxln(
    const short* __restrict__ rgbf, const float* __restrict__ g,
    const float* __restrict__ b, float* __restrict__ fq, short* __restrict__ xq)
{
    int bs = blockIdx.x, t = threadIdx.x;
    float m = -1e30f;
    for (int v = 0; v < VV; v++) m = fmaxf(m, b2f(rgbf[((size_t)(bs * VV + v)) * 256 + t]));
    fq[(size_t)bs * WW + t] = m;
    __shared__ float red[256];
    red[t] = m;
    __syncthreads();
    for (int s = 128; s > 0; s >>= 1) { if (t < s) red[t] += red[t + s]; __syncthreads(); }
    float mean = red[0] * (1.f / 256.f);
    __syncthreads();
    float d = m - mean;
    red[t] = d * d;
    __syncthreads();
    for (int s = 128; s > 0; s >>= 1) { if (t < s) red[t] += red[t + s]; __syncthreads(); }
    float var = red[0] * (1.f / 256.f);
    xq[(size_t)bs * WW + t] = f2b(d / sqrtf(var + 1e-6f) * g[t] + b[t]);
}

__global__ __launch_bounds__(256) void headk(
    const short* __restrict__ h, const float* __restrict__ ow,
    const float* __restrict__ ob, float* __restrict__ out)
{
    int b = blockIdx.x, t = threadIdx.x;
    float acc = 0.f;
    for (int s = 0; s < SS; s++) acc += b2f(h[((size_t)(b * SS + s)) * WW + t]);
    __shared__ float mean[256];
    mean[t] = acc * (1.f / 64.f);
    __syncthreads();
    if (t < 3) {
        float o = ob[t];
        for (int w = 0; w < WW; w++) o += mean[w] * ow[w * 3 + t];
        out[b * 3 + t] = o;
    }
}

// ---------------------------------------------------------------------------
#define GEMM_BF(TMv,TNv,WMv,WNv, A,Bt,bias,C,M,N,K,ldc,relu) \
  gemm_mfma<TMv,TNv,WMv,WNv,true><<<dim3((N)/(TNv),(M)/(TMv)),256,0,stream>>>((A),(Bt),(bias),nullptr,nullptr,(C),(M),(N),(K),(ldc),(relu))

extern "C" void kernel_launch(void* const* d_in, const int* in_sizes, int n_in,
                              void* d_out, int out_size, void* d_ws, size_t ws_size,
                              hipStream_t stream)
{
    const float* rgb_feat   = (const float*)d_in[0];
    const float* ray_diff   = (const float*)d_in[1];
    const int*   maskp      = (const int*)d_in[2];
    const float* pts        = (const float*)d_in[3];
    const float* ray_d      = (const float*)d_in[4];
    const float* rgbfeat_w1 = (const float*)d_in[5];
    const float* rgbfeat_b1 = (const float*)d_in[6];
    const float* rgbfeat_w2 = (const float*)d_in[7];
    const float* rgbfeat_b2 = (const float*)d_in[8];
    const float* c_ln_g = (const float*)d_in[9];
    const float* c_ln_b = (const float*)d_in[10];
    const float* c_qw   = (const float*)d_in[11];
    const float* c_kw   = (const float*)d_in[12];
    const float* c_vw   = (const float*)d_in[13];
    const float* c_pw1  = (const float*)d_in[14];
    const float* c_pb1  = (const float*)d_in[15];
    const float* c_pw2  = (const float*)d_in[16];
    const float* c_pb2  = (const float*)d_in[17];
    const float* c_aw1  = (const float*)d_in[18];
    const float* c_ab1  = (const float*)d_in[19];
    const float* c_aw2  = (const float*)d_in[20];
    const float* c_ab2  = (const float*)d_in[21];
    const float* c_ow   = (const float*)d_in[22];
    const float* c_ob   = (const float*)d_in[23];
    const float* c_fg   = (const float*)d_in[24];
    const float* c_fb   = (const float*)d_in[25];
    const float* c_fw1  = (const float*)d_in[26];
    const float* c_fb1  = (const float*)d_in[27];
    const float* c_fw2  = (const float*)d_in[28];
    const float* c_fb2  = (const float*)d_in[29];
    const float* s_ln_g = (const float*)d_in[30];
    const float* s_ln_b = (const float*)d_in[31];
    const float* s_qw   = (const float*)d_in[32];
    const float* s_kw   = (const float*)d_in[33];
    const float* s_vw   = (const float*)d_in[34];
    const float* s_ow   = (const float*)d_in[35];
    const float* s_ob   = (const float*)d_in[36];
    const float* s_fg   = (const float*)d_in[37];
    const float* s_fb   = (const float*)d_in[38];
    const float* s_fw1  = (const float*)d_in[39];
    const float* s_fb1  = (const float*)d_in[40];
    const float* s_fw2  = (const float*)d_in[41];
    const float* s_fb2  = (const float*)d_in[42];
    const float* q_w1   = (const float*)d_in[43];
    const float* q_b1   = (const float*)d_in[44];
    const float* q_w2   = (const float*)d_in[45];
    const float* q_b2   = (const float*)d_in[46];
    const float* norm_g = (const float*)d_in[47];
    const float* norm_b = (const float*)d_in[48];
    const float* out_w  = (const float*)d_in[49];
    const float* out_b  = (const float*)d_in[50];
    float* out = (float*)d_out;

    // ---- workspace carve (256B aligned) ----
    char* p = (char*)d_ws;
    auto alloc = [&](size_t bytes) { char* r = p; p += (bytes + 255) & ~(size_t)255; return r; };
    short* rgbf  = (short*)alloc((size_t)BSV * 256 * 2);
    short* hall  = (short*)alloc((size_t)DD * BSV * 32 * 2);
    short* a_in  = (short*)alloc((size_t)BSV * 256 * 2);
    short* obb   = (short*)alloc((size_t)BS * 256 * 2);
    short* xq    = (short*)alloc((size_t)BS * 256 * 2);
    short* hb    = (short*)alloc((size_t)BS * 256 * 2);
    short* catb  = (short*)alloc((size_t)BS * 384 * 2);
    short* qkv   = (short*)alloc((size_t)BS * 768 * 2);
    short* rgbp  = qkv;
    float* qf    = (float*)alloc((size_t)BS * 256 * 4);
    float* fq    = (float*)alloc((size_t)BS * 256 * 4);
    // weights
    short* w1T   = (short*)alloc(256 * 64 * 2);
    short* w2T   = (short*)alloc(256 * 256 * 2);
    short* qwT   = (short*)alloc((size_t)DD * 256 * 256 * 2);
    short* kvpT  = (short*)alloc((size_t)DD * 512 * 288 * 2);
    short* aw1T  = (short*)alloc((size_t)DD * 32 * 256 * 2);
    short* aw2T  = (short*)alloc((size_t)DD * 256 * 32 * 2);
    short* owT   = (short*)alloc((size_t)DD * 256 * 256 * 2);
    short* fw1T  = (short*)alloc((size_t)DD * 1024 * 256 * 2);
    short* fw2T  = (short*)alloc((size_t)DD * 256 * 1024 * 2);
    short* sqkvT = (short*)alloc((size_t)DD * 768 * 256 * 2);
    short* sowT  = (short*)alloc((size_t)DD * 256 * 256 * 2);
    short* sfw1T = (short*)alloc((size_t)DD * 1024 * 256 * 2);
    short* sfw2T = (short*)alloc((size_t)DD * 256 * 1024 * 2);
    short* qw1T  = (short*)alloc((size_t)4 * 256 * 384 * 2);
    short* qw2T  = (short*)alloc((size_t)4 * 256 * 256 * 2);

    // ---- batched weight conversion (one dispatch) ----
    WJobs wj; int nj = 0, totblk = 0;
    // frag=0 (row-major [N,Kpad]), frag=1 (fragment-packed; KS/ntoff/ksoff)
    auto addj = [&](const float* s, short* d, int K, int N, int frag,
                    int KS, int ntoff, int ksoff, int Kpad,
                    int zi, size_t zo, int nz) {
        WJob& J = wj.j[nj++];
        J.src = s; J.dst = d; J.K = K; J.N = N; J.frag = frag;
        J.KS = KS; J.ntoff = ntoff; J.ksoff = ksoff; J.Kpad = Kpad;
        J.zi = zi; J.zo = zo; J.gy = (K + 31) >> 5;
        J.nblk = (N >> 5) * J.gy * nz;
        totblk += J.nblk;
    };
    addj(rgbfeat_w1, w1T, 35, 256, 0, 0, 0, 0, 64, 0, 0, 1);
    addj(rgbfeat_w2, w2T, 256, 256, 0, 0, 0, 0, 256, 0, 0, 1);
    addj(c_qw,  qwT,  256, 256, 1, 8, 0, 0, 0, 65536, 65536, DD);
    addj(c_kw,  kvpT, 256, 256, 1, 9, 0, 0, 0, 65536, 147456, DD);
    addj(c_pw2, kvpT, 32, 256, 1, 9, 0, 8, 0, 8192, 147456, DD);
    addj(c_vw,  kvpT, 256, 256, 1, 9, 16, 0, 0, 65536, 147456, DD);
    addj(c_pw2, kvpT, 32, 256, 1, 9, 16, 8, 0, 8192, 147456, DD);
    addj(c_aw1, aw1T, 256, 32, 1, 8, 0, 0, 0, 8192, 8192, DD);
    addj(c_aw2, aw2T, 32, 256, 1, 1, 0, 0, 0, 8192, 8192, DD);
    addj(c_ow,  owT,  256, 256, 1, 8, 0, 0, 0, 65536, 65536, DD);
    addj(c_fw1, fw1T, 256, 1024, 1, 8, 0, 0, 0, 262144, 262144, DD);
    addj(c_fw2, fw2T, 1024, 256, 1, 32, 0, 0, 0, 262144, 262144, DD);
    addj(s_qw,  sqkvT, 256, 256, 1, 8, 0, 0, 0, 65536, 196608, DD);
    addj(s_kw,  sqkvT, 256, 256, 1, 8, 16, 0, 0, 65536, 196608, DD);
    addj(s_vw,  sqkvT, 256, 256, 1, 8, 32, 0, 0, 65536, 196608, DD);
    addj(s_ow,  sowT,  256, 256, 1, 8, 0, 0, 0, 65536, 65536, DD);
    addj(s_fw1, sfw1T, 256, 1024, 1, 8, 0, 0, 0, 262144, 262144, DD);
    addj(s_fw2, sfw2T, 1024, 256, 1, 32, 0, 0, 0, 262144, 262144, DD);
    addj(q_w1,  qw1T, 346, 256, 1, 12, 0, 0, 0, 88576, 98304, 4);
    addj(q_w2,  qw2T, 256, 256, 1, 8, 0, 0, 0, 65536, 65536, 4);
    wconv_all<<<totblk, dim3(32, 8), 0, stream>>>(wj);

    // ---- preamble ----
    catpenc<<<(BS * 128) / 256, 256, 0, stream>>>(pts, ray_d, catb);
    rgbhall<<<(BSV * 64 + DD * BSV * 32) / 256, 256, 0, stream>>>(
        rgb_feat, ray_diff, c_pw1, c_pb1, rgbp, hall);
    GEMM_BF(128, 128, 64, 64, rgbp, w1T, rgbfeat_b1, a_in, BSV, 256, 64, 256, 1);
    GEMM_BF(128, 128, 64, 64, a_in, w2T, rgbfeat_b2, rgbf, BSV, 256, 256, 256, 0);
    vmaxln<<<BS, 256, 0, stream>>>(rgbf, c_ln_g, c_ln_b, fq, xq);
    qgemm0<<<256, 256, 0, stream>>>(xq, qwT, qf);

    for (int i = 0; i < DD; i++) {
        int j = i >> 1;
        crosskv<<<BSV / 32, 256, 0, stream>>>(
            rgbf, hall + (size_t)i * BSV * 32, kvpT + (size_t)i * 147456,
            qf, maskp,
            aw1T + (size_t)i * 8192, c_ab1 + i * 32,
            aw2T + (size_t)i * 8192, c_ab2 + i * 256, obb);
        chainA<<<256, 512, 0, stream>>>(obb, fq, catb, qkv,
            owT + (size_t)i * 65536, c_ob + i * 256, c_fg + i * 256, c_fb + i * 256,
            fw1T + (size_t)i * 262144, c_fb1 + i * 1024,
            fw2T + (size_t)i * 262144, c_fb2 + i * 256,
            qw1T + (size_t)j * 98304, q_b1 + j * 256,
            qw2T + (size_t)j * 65536, q_b2 + j * 256,
            s_ln_g + i * 256, s_ln_b + i * 256,
            sqkvT + (size_t)i * 196608, !(i & 1));
        int last = (i == DD - 1);
        chainB<<<256, 512, 0, stream>>>(qkv, fq,
            sowT + (size_t)i * 65536, s_ob + i * 256, s_fg + i * 256, s_fb + i * 256,
            sfw1T + (size_t)i * 262144, s_fb1 + i * 1024,
            sfw2T + (size_t)i * 262144, s_fb2 + i * 256,
            last ? norm_g : c_ln_g + (i + 1) * 256,
            last ? norm_b : c_ln_b + (i + 1) * 256,
            last ? 1e-5f : 1e-6f,
            last ? nullptr : qwT + (size_t)(i + 1) * 65536,
            qf, last ? hb : nullptr);
    }

    headk<<<BB, 256, 0, stream>>>(hb, out_w, out_b, out);
}

// Round 7
// 867.489 us; speedup vs baseline: 1.0179x; 1.0179x over previous
//
#include <hip/hip_runtime.h>
#include <hip/hip_bf16.h>
#include <math.h>

#define BB 64
#define SS 64
#define VV 8
#define WW 256
#define DD 8
#define BS (BB*SS)        // 4096
#define BSV (BB*SS*VV)    // 32768

#define RB 392            // rowbuf stride (shorts)
#define HBs 1064          // hid stride
#define TB 264            // tmpb stride
#define AS 296            // crosskv A stride

typedef __attribute__((ext_vector_type(8))) short s8v;
typedef __attribute__((ext_vector_type(4))) float f4v;

__device__ __forceinline__ short f2b(float f) {
    __hip_bfloat16 h = __float2bfloat16(f);
    return *reinterpret_cast<short*>(&h);
}
__device__ __forceinline__ float b2f(short s) {
    __hip_bfloat16 h = *reinterpret_cast<__hip_bfloat16*>(&s);
    return __bfloat162float(h);
}

// ---------------------------------------------------------------------------
// B fragments are FRAGMENT-PACKED: bF[(k*64+lane)*8] -> one contiguous 1KB
// burst per wave per MFMA.
// rowgemm: generic (loads B inline), dual accumulator to halve the dependent
// MFMA chain. rowgemm_pre: B pre-loaded into registers (prefetched across a
// barrier). rowgemm_mix: first 8 k-steps prefetched, remainder streamed.
// ---------------------------------------------------------------------------
__device__ __forceinline__ void bload8(const short* __restrict__ bF, int lane,
                                       s8v* __restrict__ dst)
{
#pragma unroll
    for (int k = 0; k < 8; k++)
        dst[k] = *(const s8v*)&bF[(size_t)(k * 64 + lane) * 8];
}

__device__ __forceinline__ f4v rowgemm(const short* __restrict__ aL, int lda,
                                       const short* __restrict__ bF,
                                       int ksteps, int lane)
{
    int lm = lane & 15, lq = lane >> 4;
    f4v a0 = (f4v){0.f, 0.f, 0.f, 0.f};
    f4v a1 = (f4v){0.f, 0.f, 0.f, 0.f};
    int k = 0;
#pragma unroll 8
    for (; k + 1 < ksteps; k += 2) {
        s8v x0 = *(const s8v*)&aL[lm * lda + k * 32 + lq * 8];
        s8v b0 = *(const s8v*)&bF[(size_t)(k * 64 + lane) * 8];
        s8v x1 = *(const s8v*)&aL[lm * lda + (k + 1) * 32 + lq * 8];
        s8v b1 = *(const s8v*)&bF[(size_t)((k + 1) * 64 + lane) * 8];
        a0 = __builtin_amdgcn_mfma_f32_16x16x32_bf16(x0, b0, a0, 0, 0, 0);
        a1 = __builtin_amdgcn_mfma_f32_16x16x32_bf16(x1, b1, a1, 0, 0, 0);
    }
    if (k < ksteps) {
        s8v x = *(const s8v*)&aL[lm * lda + k * 32 + lq * 8];
        s8v b = *(const s8v*)&bF[(size_t)(k * 64 + lane) * 8];
        a0 = __builtin_amdgcn_mfma_f32_16x16x32_bf16(x, b, a0, 0, 0, 0);
    }
    return a0 + a1;
}

__device__ __forceinline__ f4v rowgemm_pre(const short* __restrict__ aL, int lda,
                                           const s8v* __restrict__ bp, int lane)
{
    int lm = lane & 15, lq = lane >> 4;
    f4v a0 = (f4v){0.f, 0.f, 0.f, 0.f};
    f4v a1 = (f4v){0.f, 0.f, 0.f, 0.f};
#pragma unroll
    for (int k = 0; k < 8; k += 2) {
        s8v x0 = *(const s8v*)&aL[lm * lda + k * 32 + lq * 8];
        s8v x1 = *(const s8v*)&aL[lm * lda + (k + 1) * 32 + lq * 8];
        a0 = __builtin_amdgcn_mfma_f32_16x16x32_bf16(x0, bp[k], a0, 0, 0, 0);
        a1 = __builtin_amdgcn_mfma_f32_16x16x32_bf16(x1, bp[k + 1], a1, 0, 0, 0);
    }
    return a0 + a1;
}

__device__ __forceinline__ f4v rowgemm_mix(const short* __restrict__ aL, int lda,
                                           const s8v* __restrict__ bp,
                                           const short* __restrict__ bF,
                                           int ksteps, int lane)
{
    int lm = lane & 15, lq = lane >> 4;
    f4v a0 = (f4v){0.f, 0.f, 0.f, 0.f};
    f4v a1 = (f4v){0.f, 0.f, 0.f, 0.f};
#pragma unroll
    for (int k = 0; k < 8; k += 2) {
        s8v x0 = *(const s8v*)&aL[lm * lda + k * 32 + lq * 8];
        s8v x1 = *(const s8v*)&aL[lm * lda + (k + 1) * 32 + lq * 8];
        a0 = __builtin_amdgcn_mfma_f32_16x16x32_bf16(x0, bp[k], a0, 0, 0, 0);
        a1 = __builtin_amdgcn_mfma_f32_16x16x32_bf16(x1, bp[k + 1], a1, 0, 0, 0);
    }
#pragma unroll 8
    for (int k = 8; k + 1 < ksteps; k += 2) {
        s8v x0 = *(const s8v*)&aL[lm * lda + k * 32 + lq * 8];
        s8v b0 = *(const s8v*)&bF[(size_t)(k * 64 + lane) * 8];
        s8v x1 = *(const s8v*)&aL[lm * lda + (k + 1) * 32 + lq * 8];
        s8v b1 = *(const s8v*)&bF[(size_t)((k + 1) * 64 + lane) * 8];
        a0 = __builtin_amdgcn_mfma_f32_16x16x32_bf16(x0, b0, a0, 0, 0, 0);
        a1 = __builtin_amdgcn_mfma_f32_16x16x32_bf16(x1, b1, a1, 0, 0, 0);
    }
    return a0 + a1;
}

// ---------------------------------------------------------------------------
// In-block LayerNorm of 16 rows x 256 cols held in registers v[t][r].
// Fused-moment version (var = E[x^2]-mean^2): 2 barriers instead of 4.
// 8-wave: each wave owns 2 column-tiles (32 cols). red = 256 floats.
// ---------------------------------------------------------------------------
__device__ __forceinline__ void ln_rows(
    float v[2][4], const float* __restrict__ g, const float* __restrict__ b,
    float eps, short* rowbuf, float* red, int w, int lm, int lq,
    short* __restrict__ outG, int row0)
{
    float ps[4], pq[4];
#pragma unroll
    for (int r = 0; r < 4; r++) {
        ps[r] = v[0][r] + v[1][r];
        pq[r] = v[0][r] * v[0][r] + v[1][r] * v[1][r];
    }
#pragma unroll
    for (int m = 1; m < 16; m <<= 1)
#pragma unroll
        for (int r = 0; r < 4; r++) {
            ps[r] += __shfl_xor(ps[r], m);
            pq[r] += __shfl_xor(pq[r], m);
        }
    if (lm == 0)
#pragma unroll
        for (int r = 0; r < 4; r++) {
            red[(lq * 4 + r) * 16 + w] = ps[r];
            red[(lq * 4 + r) * 16 + 8 + w] = pq[r];
        }
    __syncthreads();
    float mean[4], inv[4];
#pragma unroll
    for (int r = 0; r < 4; r++) {
        int row = lq * 4 + r;
        float s = 0.f, s2 = 0.f;
#pragma unroll
        for (int q = 0; q < 8; q++) { s += red[row * 16 + q]; s2 += red[row * 16 + 8 + q]; }
        mean[r] = s * (1.f / 256.f);
        float var = fmaxf(s2 * (1.f / 256.f) - mean[r] * mean[r], 0.f);
        inv[r] = rsqrtf(var + eps);
    }
#pragma unroll
    for (int t = 0; t < 2; t++) {
        int col = (w * 2 + t) * 16 + lm;
        float gc = g[col], bc = b[col];
#pragma unroll
        for (int r = 0; r < 4; r++) {
            float val = (v[t][r] - mean[r]) * inv[r] * gc + bc;
            rowbuf[(lq * 4 + r) * RB + col] = f2b(val);
            if (outG) outG[(size_t)(row0 + lq * 4 + r) * 256 + col] = f2b(val);
        }
    }
    __syncthreads();
}

// ---------------------------------------------------------------------------
// chainA: ow+res -> LN(c_fg) -> fw1 -> fw2+res -> [even: cat->q1->q2]
//         -> write fq -> LN(s_ln) -> sqkv.  Block = 16 rows, 512 thr, grid 256.
// B-fragment loads for each phase are prefetched into registers BEFORE the
// preceding barrier so the L2 latency hides under LN/staging barriers.
// ---------------------------------------------------------------------------
__global__ __launch_bounds__(512) void chainA(
    const short* __restrict__ obb, float* __restrict__ fq,
    const short* __restrict__ catb, short* __restrict__ qkv,
    const short* __restrict__ owT, const float* __restrict__ c_ob,
    const float* __restrict__ c_fg, const float* __restrict__ c_fb,
    const short* __restrict__ fw1T, const float* __restrict__ c_fb1,
    const short* __restrict__ fw2T, const float* __restrict__ c_fb2,
    const short* __restrict__ qw1T, const float* __restrict__ q_b1,
    const short* __restrict__ qw2T, const float* __restrict__ q_b2,
    const float* __restrict__ s_ln_g, const float* __restrict__ s_ln_b,
    const short* __restrict__ sqkvT, int even)
{
    __shared__ __align__(16) short rowbuf[16 * RB];
    __shared__ __align__(16) short hid[16 * HBs];
    __shared__ __align__(16) short tmpb[16 * TB];
    __shared__ float red[256];
    int tid = threadIdx.x, lane = tid & 63, w = tid >> 6;  // w in [0,8)
    int lm = lane & 15, lq = lane >> 4;
    int row0 = blockIdx.x * 16;
    // prefetch ow B-fragments (overlaps obb staging + barrier)
    s8v bo[16];
    bload8(owT + (size_t)(w * 2 + 0) * 4096, lane, bo);
    bload8(owT + (size_t)(w * 2 + 1) * 4096, lane, bo + 8);
    {
        int r = tid >> 5, c = (tid & 31) * 8;
        *(s8v*)&rowbuf[r * RB + c] = *(const s8v*)&obb[(size_t)(row0 + r) * 256 + c];
    }
    __syncthreads();
    float fqreg[2][4];
#pragma unroll
    for (int t = 0; t < 2; t++) {
        f4v o = rowgemm_pre(rowbuf, RB, bo + t * 8, lane);
        int col = (w * 2 + t) * 16 + lm;
        float bb = c_ob[col];
#pragma unroll
        for (int r = 0; r < 4; r++)
            fqreg[t][r] = o[r] + bb + fq[(size_t)(row0 + lq * 4 + r) * 256 + col];
    }
    // prefetch fw1 tiles 0,1 (overlaps the LN barriers)
    s8v bf[16];
    bload8(fw1T + (size_t)(w * 8 + 0) * 4096, lane, bf);
    bload8(fw1T + (size_t)(w * 8 + 1) * 4096, lane, bf + 8);
    ln_rows(fqreg, c_fg, c_fb, 1e-6f, rowbuf, red, w, lm, lq, nullptr, row0);
#pragma unroll
    for (int t = 0; t < 8; t++) {
        f4v o = (t < 2) ? rowgemm_pre(rowbuf, RB, bf + t * 8, lane)
                        : rowgemm(rowbuf, RB, fw1T + (size_t)(w * 8 + t) * 4096, 8, lane);
        int col = (w * 8 + t) * 16 + lm;
        float bb = c_fb1[col];
#pragma unroll
        for (int r = 0; r < 4; r++)
            hid[(lq * 4 + r) * HBs + col] = f2b(fmaxf(o[r] + bb, 0.f));
    }
    // prefetch fw2 first 8 k-steps of both tiles (overlaps hid barrier)
    s8v b2[16];
    bload8(fw2T + (size_t)(w * 2 + 0) * 16384, lane, b2);
    bload8(fw2T + (size_t)(w * 2 + 1) * 16384, lane, b2 + 8);
    __syncthreads();
#pragma unroll
    for (int t = 0; t < 2; t++) {
        f4v o = rowgemm_mix(hid, HBs, b2 + t * 8,
                            fw2T + (size_t)(w * 2 + t) * 16384, 32, lane);
        int col = (w * 2 + t) * 16 + lm;
        float bb = c_fb2[col];
#pragma unroll
        for (int r = 0; r < 4; r++)
            fqreg[t][r] = o[r] + bb + fqreg[t][r];
    }
    if (even) {
#pragma unroll
        for (int t = 0; t < 2; t++) {
            int col = (w * 2 + t) * 16 + lm;
#pragma unroll
            for (int r = 0; r < 4; r++)
                rowbuf[(lq * 4 + r) * RB + col] = f2b(fqreg[t][r]);
        }
        if (tid < 256) {
            int r = tid >> 4, c = (tid & 15) * 8;
            *(s8v*)&rowbuf[r * RB + 256 + c] = *(const s8v*)&catb[(size_t)(row0 + r) * 384 + 256 + c];
        }
        // prefetch q1 first 8 k-steps of both tiles (overlaps barrier)
        s8v bq[16];
        bload8(qw1T + (size_t)(w * 2 + 0) * 6144, lane, bq);
        bload8(qw1T + (size_t)(w * 2 + 1) * 6144, lane, bq + 8);
        __syncthreads();
#pragma unroll
        for (int t = 0; t < 2; t++) {
            f4v o = rowgemm_mix(rowbuf, RB, bq + t * 8,
                                qw1T + (size_t)(w * 2 + t) * 6144, 12, lane);
            int col = (w * 2 + t) * 16 + lm;
            float bb = q_b1[col];
#pragma unroll
            for (int r = 0; r < 4; r++)
                tmpb[(lq * 4 + r) * TB + col] = f2b(fmaxf(o[r] + bb, 0.f));
        }
        // prefetch q2 (full, both tiles) across the tmpb barrier
        s8v bq2[16];
        bload8(qw2T + (size_t)(w * 2 + 0) * 4096, lane, bq2);
        bload8(qw2T + (size_t)(w * 2 + 1) * 4096, lane, bq2 + 8);
        __syncthreads();
#pragma unroll
        for (int t = 0; t < 2; t++) {
            f4v o = rowgemm_pre(tmpb, TB, bq2 + t * 8, lane);
            int col = (w * 2 + t) * 16 + lm;
            float bb = q_b2[col];
#pragma unroll
            for (int r = 0; r < 4; r++)
                fqreg[t][r] = o[r] + bb;
        }
    }
#pragma unroll
    for (int t = 0; t < 2; t++) {
        int col = (w * 2 + t) * 16 + lm;
#pragma unroll
        for (int r = 0; r < 4; r++)
            fq[(size_t)(row0 + lq * 4 + r) * 256 + col] = fqreg[t][r];
    }
    // prefetch sqkv tiles 0,1 (overlaps the LN barriers)
    s8v bs[16];
    bload8(sqkvT + (size_t)(w * 6 + 0) * 4096, lane, bs);
    bload8(sqkvT + (size_t)(w * 6 + 1) * 4096, lane, bs + 8);
    ln_rows(fqreg, s_ln_g, s_ln_b, 1e-6f, rowbuf, red, w, lm, lq, nullptr, row0);
#pragma unroll
    for (int t = 0; t < 6; t++) {
        f4v o = (t < 2) ? rowgemm_pre(rowbuf, RB, bs + t * 8, lane)
                        : rowgemm(rowbuf, RB, sqkvT + (size_t)(w * 6 + t) * 4096, 8, lane);
        int col = (w * 6 + t) * 16 + lm;
#pragma unroll
        for (int r = 0; r < 4; r++)
            qkv[(size_t)(row0 + lq * 4 + r) * 768 + col] = f2b(o[r]);
    }
}

// ---------------------------------------------------------------------------
// chainB: sow+res -> LN(s_fg) -> sfw1 -> sfw2+res -> write fq ->
//         LN(next c_ln | final norm[->hb]) -> qw_next -> qf.  512 threads.
// Same cross-barrier B-prefetch structure as chainA.
// ---------------------------------------------------------------------------
__global__ __launch_bounds__(512) void chainB(
    const short* __restrict__ obb, float* __restrict__ fq,
    const short* __restrict__ sowT, const float* __restrict__ s_ob,
    const float* __restrict__ s_fg, const float* __restrict__ s_fb,
    const short* __restrict__ sfw1T, const float* __restrict__ s_fb1,
    const short* __restrict__ sfw2T, const float* __restrict__ s_fb2,
    const float* __restrict__ ln2_g, const float* __restrict__ ln2_b, float eps2,
    const short* __restrict__ qwTn, float* __restrict__ qf,
    short* __restrict__ hbG)
{
    __shared__ __align__(16) short rowbuf[16 * RB];
    __shared__ __align__(16) short hid[16 * HBs];
    __shared__ float red[256];
    int tid = threadIdx.x, lane = tid & 63, w = tid >> 6;
    int lm = lane & 15, lq = lane >> 4;
    int row0 = blockIdx.x * 16;
    s8v bo[16];
    bload8(sowT + (size_t)(w * 2 + 0) * 4096, lane, bo);
    bload8(sowT + (size_t)(w * 2 + 1) * 4096, lane, bo + 8);
    {
        int r = tid >> 5, c = (tid & 31) * 8;
        *(s8v*)&rowbuf[r * RB + c] = *(const s8v*)&obb[(size_t)(row0 + r) * 256 + c];
    }
    __syncthreads();
    float fqreg[2][4];
#pragma unroll
    for (int t = 0; t < 2; t++) {
        f4v o = rowgemm_pre(rowbuf, RB, bo + t * 8, lane);
        int col = (w * 2 + t) * 16 + lm;
        float bb = s_ob[col];
#pragma unroll
        for (int r = 0; r < 4; r++)
            fqreg[t][r] = o[r] + bb + fq[(size_t)(row0 + lq * 4 + r) * 256 + col];
    }
    s8v bf[16];
    bload8(sfw1T + (size_t)(w * 8 + 0) * 4096, lane, bf);
    bload8(sfw1T + (size_t)(w * 8 + 1) * 4096, lane, bf + 8);
    ln_rows(fqreg, s_fg, s_fb, 1e-6f, rowbuf, red, w, lm, lq, nullptr, row0);
#pragma unroll
    for (int t = 0; t < 8; t++) {
        f4v o = (t < 2) ? rowgemm_pre(rowbuf, RB, bf + t * 8, lane)
                        : rowgemm(rowbuf, RB, sfw1T + (size_t)(w * 8 + t) * 4096, 8, lane);
        int col = (w * 8 + t) * 16 + lm;
        float bb = s_fb1[col];
#pragma unroll
        for (int r = 0; r < 4; r++)
            hid[(lq * 4 + r) * HBs + col] = f2b(fmaxf(o[r] + bb, 0.f));
    }
    s8v b2[16];
    bload8(sfw2T + (size_t)(w * 2 + 0) * 16384, lane, b2);
    bload8(sfw2T + (size_t)(w * 2 + 1) * 16384, lane, b2 + 8);
    __syncthreads();
#pragma unroll
    for (int t = 0; t < 2; t++) {
        f4v o = rowgemm_mix(hid, HBs, b2 + t * 8,
                            sfw2T + (size_t)(w * 2 + t) * 16384, 32, lane);
        int col = (w * 2 + t) * 16 + lm;
        float bb = s_fb2[col];
#pragma unroll
        for (int r = 0; r < 4; r++)
            fqreg[t][r] = o[r] + bb + fqreg[t][r];
    }
#pragma unroll
    for (int t = 0; t < 2; t++) {
        int col = (w * 2 + t) * 16 + lm;
#pragma unroll
        for (int r = 0; r < 4; r++)
            fq[(size_t)(row0 + lq * 4 + r) * 256 + col] = fqreg[t][r];
    }
    s8v bq[16];
    if (qwTn) {
        bload8(qwTn + (size_t)(w * 2 + 0) * 4096, lane, bq);
        bload8(qwTn + (size_t)(w * 2 + 1) * 4096, lane, bq + 8);
    }
    ln_rows(fqreg, ln2_g, ln2_b, eps2, rowbuf, red, w, lm, lq, hbG, row0);
    if (qwTn) {
#pragma unroll
        for (int t = 0; t < 2; t++) {
            f4v o = rowgemm_pre(rowbuf, RB, bq + t * 8, lane);
            int col = (w * 2 + t) * 16 + lm;
#pragma unroll
            for (int r = 0; r < 4; r++)
                qf[(size_t)(row0 + lq * 4 + r) * 256 + col] = o[r];
        }
    }
}

// layer-0 q projection: qf = xq @ qw0 (frag-packed), block = 16 rows
__global__ __launch_bounds__(256) void qgemm0(
    const short* __restrict__ xq, const short* __restrict__ qwT0,
    float* __restrict__ qf)
{
    __shared__ __align__(16) short rowbuf[16 * TB];
    int tid = threadIdx.x, lane = tid & 63, w = tid >> 6;
    int lm = lane & 15, lq = lane >> 4;
    int row0 = blockIdx.x * 16;
    {
        int r = tid >> 4, c = (tid & 15) * 16;
        *(s8v*)&rowbuf[r * TB + c]     = *(const s8v*)&xq[(size_t)(row0 + r) * 256 + c];
        *(s8v*)&rowbuf[r * TB + c + 8] = *(const s8v*)&xq[(size_t)(row0 + r) * 256 + c + 8];
    }
    __syncthreads();
#pragma unroll
    for (int t = 0; t < 4; t++) {
        f4v o = rowgemm(rowbuf, TB, qwT0 + (size_t)(w * 4 + t) * 4096, 8, lane);
        int col = (w * 4 + t) * 16 + lm;
#pragma unroll
        for (int r = 0; r < 4; r++)
            qf[(size_t)(row0 + lq * 4 + r) * 256 + col] = o[r];
    }
}

// ---------------------------------------------------------------------------
// crosskv: fused kv-projection + cross-attention. Block = 32 kv rows
// (4 samples), grid 1024. All weights fragment-packed (kvp KS=9).
// ---------------------------------------------------------------------------
__global__ __launch_bounds__(256) void crosskv(
    const short* __restrict__ rgbf, const short* __restrict__ hall_l,
    const short* __restrict__ kvpT_l, const float* __restrict__ qf,
    const int* __restrict__ mask,
    const short* __restrict__ aw1T_l, const float* __restrict__ ab1,
    const short* __restrict__ aw2T_l, const float* __restrict__ ab2,
    short* __restrict__ obb)
{
    __shared__ __align__(16) short A_s[32 * AS];
    __shared__ __align__(16) short a_s[32 * 264];
    __shared__ __align__(16) short ph_s[32 * 40];
    __shared__ int msk[32];
    int blk = blockIdx.x, tid = threadIdx.x;
    int row0 = blk * 32, bs0 = blk * 4;
    int lane = tid & 63, w = tid >> 6, lm = lane & 15, lq = lane >> 4;
    if (tid < 32) msk[tid] = mask[bs0 * 8 + tid];
#pragma unroll
    for (int i = 0; i < 4; i++) {
        int e = tid + i * 256;
        int r = e >> 5, c = (e & 31) << 3;
        *(s8v*)&A_s[r * AS + c] = *(const s8v*)&rgbf[(size_t)(row0 + r) * 256 + c];
    }
    if (tid < 128) {
        int r = tid >> 2, c = (tid & 3) << 3;
        *(s8v*)&A_s[r * AS + 256 + c] = *(const s8v*)&hall_l[(size_t)(row0 + r) * 32 + c];
    }
    __syncthreads();
    // k-half: ntile = w*4+j4
#pragma unroll
    for (int j4 = 0; j4 < 4; j4++) {
        int nt = w * 4 + j4;
#pragma unroll
        for (int i = 0; i < 2; i++) {
            f4v acc = rowgemm(&A_s[i * 16 * AS], AS, kvpT_l + (size_t)nt * 9 * 512, 9, lane);
#pragma unroll
            for (int r = 0; r < 4; r++) {
                int row = i * 16 + lq * 4 + r, col = nt * 16 + lm;
                float q = qf[(size_t)(bs0 + (row >> 3)) * 256 + col];
                a_s[row * 264 + col] = f2b(acc[r] - q);
            }
        }
    }
    __syncthreads();
    // ph = relu(a_in @ aw1 + ab1)
    {
        int i = w >> 1, j = w & 1;
        f4v acc = rowgemm(&a_s[i * 16 * 264], 264, aw1T_l + (size_t)j * 4096, 8, lane);
        int col = j * 16 + lm;
        float bb = ab1[col];
#pragma unroll
        for (int r = 0; r < 4; r++)
            ph_s[(i * 16 + lq * 4 + r) * 40 + col] = f2b(fmaxf(acc[r] + bb, 0.f));
    }
    __syncthreads();
    // a3 = ph @ aw2 (KS=1)
    f4v a3[2][4];
#pragma unroll
    for (int i = 0; i < 2; i++) {
#pragma unroll
        for (int j4 = 0; j4 < 4; j4++) {
            int nt = w * 4 + j4;
            a3[i][j4] = rowgemm(&ph_s[i * 16 * 40], 40, aw2T_l + (size_t)nt * 512, 1, lane);
        }
    }
    // v-half: ntile = 16 + w*4+j4
#pragma unroll
    for (int j4 = 0; j4 < 4; j4++) {
        int nt = w * 4 + j4;
#pragma unroll
        for (int i = 0; i < 2; i++) {
            f4v acc = rowgemm(&A_s[i * 16 * AS], AS, kvpT_l + (size_t)(16 + nt) * 9 * 512, 9, lane);
#pragma unroll
            for (int r = 0; r < 4; r++)
                a_s[(i * 16 + lq * 4 + r) * 264 + nt * 16 + lm] = f2b(acc[r]);
        }
    }
    __syncthreads();
    // masked softmax over views + weighted sum
#pragma unroll
    for (int i = 0; i < 2; i++) {
        int sample = i * 2 + (lq >> 1);
        int mk[4];
#pragma unroll
        for (int r = 0; r < 4; r++) mk[r] = msk[sample * 8 + (lq & 1) * 4 + r];
#pragma unroll
        for (int j4 = 0; j4 < 4; j4++) {
            int col = (w * 4 + j4) * 16 + lm;
            float bv = ab2[col];
            float vals[4];
#pragma unroll
            for (int r = 0; r < 4; r++) vals[r] = mk[r] ? (a3[i][j4][r] + bv) : -1e9f;
            float mx = fmaxf(fmaxf(vals[0], vals[1]), fmaxf(vals[2], vals[3]));
            mx = fmaxf(mx, __shfl_xor(mx, 16));
            float ev[4], s = 0.f;
#pragma unroll
            for (int r = 0; r < 4; r++) { ev[r] = expf(vals[r] - mx); s += ev[r]; }
            s += __shfl_xor(s, 16);
            float o = 0.f;
#pragma unroll
            for (int r = 0; r < 4; r++)
                o += ev[r] * b2f(a_s[(i * 16 + lq * 4 + r) * 264 + col]);
            o += __shfl_xor(o, 16);
            o /= s;
            if (!(lq & 1)) obb[(size_t)(bs0 + sample) * 256 + col] = f2b(o);
        }
    }
}

// ---------------------------------------------------------------------------
// bf16 MFMA GEMM (BK=32, LDS stride 40) — preamble only (row-major B^T).
// ---------------------------------------------------------------------------
template<int TM, int TN, int WM, int WN, bool OUTBF>
__global__ __launch_bounds__(256) void gemm_mfma(
    const short* __restrict__ A, const short* __restrict__ Bt,
    const float* __restrict__ bias, const float* __restrict__ res,
    float* __restrict__ Cf, short* __restrict__ Cb,
    int M, int N, int K, int ldc, int relu)
{
    constexpr int MT  = WM / 16;
    constexpr int NT  = WN / 16;
    constexpr int RWN = TN / WN;
    __shared__ __align__(16) short As[TM * 40];
    __shared__ __align__(16) short Bs[TN * 40];
    int tid = threadIdx.x;
    int m0 = blockIdx.y * TM, n0 = blockIdx.x * TN;
    int lane = tid & 63, w = tid >> 6;
    int lm = lane & 15, lq = lane >> 4;
    int wm = (w / RWN) * WM, wn = (w % RWN) * WN;
    f4v acc[MT][NT];
#pragma unroll
    for (int i = 0; i < MT; i++)
#pragma unroll
        for (int j = 0; j < NT; j++) acc[i][j] = (f4v){0.f, 0.f, 0.f, 0.f};

    for (int k0 = 0; k0 < K; k0 += 32) {
        for (int c = tid; c < TM * 4; c += 256) {
            int r = c >> 2, kc = (c & 3) << 3;
            *(s8v*)&As[r * 40 + kc] = *(const s8v*)&A[(size_t)(m0 + r) * K + k0 + kc];
        }
        for (int c = tid; c < TN * 4; c += 256) {
            int r = c >> 2, kc = (c & 3) << 3;
            *(s8v*)&Bs[r * 40 + kc] = *(const s8v*)&Bt[(size_t)(n0 + r) * K + k0 + kc];
        }
        __syncthreads();
        s8v af[MT], bfv[NT];
#pragma unroll
        for (int i = 0; i < MT; i++)
            af[i] = *(const s8v*)&As[(wm + i * 16 + lm) * 40 + lq * 8];
#pragma unroll
        for (int j = 0; j < NT; j++)
            bfv[j] = *(const s8v*)&Bs[(wn + j * 16 + lm) * 40 + lq * 8];
#pragma unroll
        for (int i = 0; i < MT; i++)
#pragma unroll
            for (int j = 0; j < NT; j++)
                acc[i][j] = __builtin_amdgcn_mfma_f32_16x16x32_bf16(af[i], bfv[j], acc[i][j], 0, 0, 0);
        __syncthreads();
    }
#pragma unroll
    for (int i = 0; i < MT; i++) {
        int row = m0 + wm + i * 16 + lq * 4;
#pragma unroll
        for (int j = 0; j < NT; j++) {
            int col = n0 + wn + j * 16 + lm;
            float bv = bias ? bias[col] : 0.f;
#pragma unroll
            for (int r = 0; r < 4; r++) {
                float v = acc[i][j][r] + bv;
                if (relu) v = fmaxf(v, 0.f);
                size_t idx = (size_t)(row + r) * ldc + col;
                if (OUTBF) {
                    Cb[idx] = f2b(v);
                } else {
                    if (res) v += res[idx];
                    Cf[idx] = v;
                }
            }
        }
    }
}

// ---------------------------------------------------------------------------
// Batched weight convert: fp32 [K,N] -> bf16, either row-major [N,Kpad]
// (frag=0) or MFMA-fragment-packed [ntile][kstep][lane][8] (frag=1).
// ---------------------------------------------------------------------------
struct WJob {
    const float* src; short* dst;
    int K, N, KS, ntoff, ksoff, Kpad, zi, gy, nblk, frag;
    size_t zo;
};
struct WJobs { WJob j[20]; };

__global__ void wconv_all(WJobs jobs)
{
    __shared__ float t[32][33];
    int b = blockIdx.x, ji = 0;
    while (b >= jobs.j[ji].nblk) { b -= jobs.j[ji].nblk; ji++; }
    WJob J = jobs.j[ji];
    int gx = J.N >> 5;
    int z = b / (gx * J.gy);
    int rem = b - z * (gx * J.gy);
    int by = rem / gx, bx = rem - by * gx;
    const float* W = J.src + (size_t)z * J.zi;
    short* Wt = J.dst + (size_t)z * J.zo;
    int n0 = bx * 32, k0 = by * 32;
    int tx = threadIdx.x, ty = threadIdx.y;
#pragma unroll
    for (int i = 0; i < 4; i++) {
        int k = k0 + ty + i * 8;
        t[ty + i * 8][tx] = (k < J.K) ? W[(size_t)k * J.N + n0 + tx] : 0.f;
    }
    __syncthreads();
    if (J.frag) {
        if (ty < 4) {
            int n = n0 + tx;
            int nt = J.ntoff + (n >> 4), lmm = n & 15;
            int ks = J.ksoff + (k0 >> 5);
            s8v o;
#pragma unroll
            for (int jj = 0; jj < 8; jj++) o[jj] = f2b(t[ty * 8 + jj][tx]);
            *(s8v*)&Wt[(((size_t)nt * J.KS + ks) * 64 + ty * 16 + lmm) * 8] = o;
        }
    } else {
#pragma unroll
        for (int i = 0; i < 4; i++) {
            int n = n0 + ty + i * 8;
            Wt[(size_t)n * J.Kpad + k0 + tx] = f2b(t[tx][ty + i * 8]);
        }
    }
}

// catb tail computed directly from pts/ray_d (penc inline)
__global__ void catpenc(const float* __restrict__ pts, const float* __restrict__ ray_d,
                        short* __restrict__ catb)
{
    int idx = blockIdx.x * 256 + threadIdx.x;
    int bs = idx >> 7, c = idx & 127;
    float v = 0.f;
    if (c < 63) {
        if (c < 3) v = pts[bs * 3 + c];
        else {
            int e = c - 3; int d, k; bool sn;
            if (e < 30) { d = e / 10; k = e - d * 10; sn = true; }
            else { e -= 30; d = e / 10; k = e - d * 10; sn = false; }
            float ang = pts[bs * 3 + d] * (float)(1 << k);
            v = sn ? sinf(ang) : cosf(ang);
        }
    } else if (c < 90) {
        int e = c - 63, b = bs >> 6;
        float x = ray_d[b * 3], y = ray_d[b * 3 + 1], z = ray_d[b * 3 + 2];
        float inv = rsqrtf(x * x + y * y + z * z);
        float vv[3] = {x * inv, y * inv, z * inv};
        if (e < 3) v = vv[e];
        else if (e < 15) { int d = (e - 3) >> 2, k = (e - 3) & 3; v = sinf(vv[d] * (float)(1 << k)); }
        else { int d = (e - 15) >> 2, k = (e - 15) & 3; v = cosf(vv[d] * (float)(1 << k)); }
    }
    catb[(size_t)bs * 384 + 256 + c] = f2b(v);
}

// rgb_feat pad-convert + hall (all 8 layers) in one launch
__global__ void rgbhall(const float* __restrict__ rgb_feat, const float* __restrict__ rdiff,
                        const float* __restrict__ pw1, const float* __restrict__ pb1,
                        short* __restrict__ rgbp, short* __restrict__ hall)
{
    int idx = blockIdx.x * 256 + threadIdx.x;
    if (idx < BSV * 64) {
        int row = idx >> 6, col = idx & 63;
        rgbp[idx] = f2b(col < 35 ? rgb_feat[row * 35 + col] : 0.f);
    } else {
        int k = idx - BSV * 64;
        int t = k & 31, row = (k >> 5) & (BSV - 1), l = k >> 20;
        float a = pb1[l * 32 + t];
        for (int c = 0; c < 4; c++) a += rdiff[row * 4 + c] * pw1[l * 128 + c * 32 + t];
        hall[k] = f2b(fmaxf(a, 0.f));
    }
}

// view-max + layer-0 LayerNorm fused
__global__ __launch_bounds__(256) void vmaxln(
    const short* __restrict__ rgbf, const float* __restrict__ g,
    const float* __restrict__ b, float* __restrict__ fq, short* __restrict__ xq)
{
    int bs = blockIdx.x, t = threadIdx.x;
    float m = -1e30f;
    for (int v = 0; v < VV; v++) m = fmaxf(m, b2f(rgbf[((size_t)(bs * VV + v)) * 256 + t]));
    fq[(size_t)bs * WW + t] = m;
    __shared__ float red[256];
    red[t] = m;
    __syncthreads();
    for (int s = 128; s > 0; s >>= 1) { if (t < s) red[t] += red[t + s]; __syncthreads(); }
    float mean = red[0] * (1.f / 256.f);
    __syncthreads();
    float d = m - mean;
    red[t] = d * d;
    __syncthreads();
    for (int s = 128; s > 0; s >>= 1) { if (t < s) red[t] += red[t + s]; __syncthreads(); }
    float var = red[0] * (1.f / 256.f);
    xq[(size_t)bs * WW + t] = f2b(d / sqrtf(var + 1e-6f) * g[t] + b[t]);
}

// ---------------------------------------------------------------------------
// MFMA self-attention: one block per (b,h), 4 waves — each wave owns one
// 16-row query tile (softmax is row-local, so no cross-wave reduction).
// QKV packed bf16 [4096,768].
// ---------------------------------------------------------------------------
__global__ __launch_bounds__(256) void attn_mfma(
    const short* __restrict__ QKV, short* __restrict__ O)
{
    __shared__ __align__(16) short P[64 * 72];
    __shared__ __align__(16) short Vt[64 * 72];
    int blk = blockIdx.x;
    int b = blk >> 2, h = blk & 3;
    int tid = threadIdx.x, lane = tid & 63, w = tid >> 6;
    int lm = lane & 15, lq = lane >> 4;
    const short* base = QKV + (size_t)b * 64 * 768 + h * 64;
    {
        int row = tid & 63, c0 = (tid >> 6) * 2;
        const short* vrow = base + 512 + (size_t)row * 768;
#pragma unroll
        for (int c = c0; c < c0 + 2; c++) {
            s8v v = *(const s8v*)&vrow[c * 8];
#pragma unroll
            for (int j = 0; j < 8; j++)
                Vt[(c * 8 + j) * 72 + row] = v[j];
        }
    }
    s8v qfr[2], kf[4][2];
#pragma unroll
    for (int c = 0; c < 2; c++) {
        qfr[c] = *(const s8v*)&base[(size_t)(w * 16 + lm) * 768 + c * 32 + lq * 8];
#pragma unroll
        for (int j = 0; j < 4; j++)
            kf[j][c] = *(const s8v*)&base[(size_t)(j * 16 + lm) * 768 + 256 + c * 32 + lq * 8];
    }
    f4v acc[4];
#pragma unroll
    for (int j = 0; j < 4; j++) acc[j] = (f4v){0.f, 0.f, 0.f, 0.f};
#pragma unroll
    for (int c = 0; c < 2; c++)
#pragma unroll
        for (int j = 0; j < 4; j++)
            acc[j] = __builtin_amdgcn_mfma_f32_16x16x32_bf16(qfr[c], kf[j][c], acc[j], 0, 0, 0);
#pragma unroll
    for (int r = 0; r < 4; r++) {
        float lv[4];
#pragma unroll
        for (int j = 0; j < 4; j++) lv[j] = acc[j][r] * 0.125f;
        float mx = fmaxf(fmaxf(lv[0], lv[1]), fmaxf(lv[2], lv[3]));
        for (int d = 1; d < 16; d <<= 1) mx = fmaxf(mx, __shfl_xor(mx, d));
        float sum = 0.f;
#pragma unroll
        for (int j = 0; j < 4; j++) { lv[j] = expf(lv[j] - mx); sum += lv[j]; }
        for (int d = 1; d < 16; d <<= 1) sum += __shfl_xor(sum, d);
        float inv = 1.f / sum;
        int row = w * 16 + lq * 4 + r;
#pragma unroll
        for (int j = 0; j < 4; j++)
            P[row * 72 + j * 16 + lm] = f2b(lv[j] * inv);
    }
    __syncthreads();
    s8v af[2], bf[4][2];
#pragma unroll
    for (int c = 0; c < 2; c++) {
        af[c] = *(const s8v*)&P[(w * 16 + lm) * 72 + c * 32 + lq * 8];
#pragma unroll
        for (int j = 0; j < 4; j++)
            bf[j][c] = *(const s8v*)&Vt[(j * 16 + lm) * 72 + c * 32 + lq * 8];
    }
    f4v o2[4];
#pragma unroll
    for (int j = 0; j < 4; j++) o2[j] = (f4v){0.f, 0.f, 0.f, 0.f};
#pragma unroll
    for (int c = 0; c < 2; c++)
#pragma unroll
        for (int j = 0; j < 4; j++)
            o2[j] = __builtin_amdgcn_mfma_f32_16x16x32_bf16(af[c], bf[j][c], o2[j], 0, 0, 0);
#pragma unroll
    for (int j = 0; j < 4; j++)
#pragma unroll
        for (int r = 0; r < 4; r++) {
            int s = w * 16 + lq * 4 + r, d = j * 16 + lm;
            O[(size_t)(b * 64 + s) * 256 + h * 64 + d] = f2b(o2[j][r]);
        }
}

__global__ __launch_bounds__(256) void headk(
    const short* __restrict__ h, const float* __restrict__ ow,
    const float* __restrict__ ob, float* __restrict__ out)
{
    int b = blockIdx.x, t = threadIdx.x;
    float acc = 0.f;
    for (int s = 0; s < SS; s++) acc += b2f(h[((size_t)(b * SS + s)) * WW + t]);
    __shared__ float mean[256];
    mean[t] = acc * (1.f / 64.f);
    __syncthreads();
    if (t < 3) {
        float o = ob[t];
        for (int w = 0; w < WW; w++) o += mean[w] * ow[w * 3 + t];
        out[b * 3 + t] = o;
    }
}

// ---------------------------------------------------------------------------
#define GEMM_BF(TMv,TNv,WMv,WNv, A,Bt,bias,C,M,N,K,ldc,relu) \
  gemm_mfma<TMv,TNv,WMv,WNv,true><<<dim3((N)/(TNv),(M)/(TMv)),256,0,stream>>>((A),(Bt),(bias),nullptr,nullptr,(C),(M),(N),(K),(ldc),(relu))

extern "C" void kernel_launch(void* const* d_in, const int* in_sizes, int n_in,
                              void* d_out, int out_size, void* d_ws, size_t ws_size,
                              hipStream_t stream)
{
    const float* rgb_feat   = (const float*)d_in[0];
    const float* ray_diff   = (const float*)d_in[1];
    const int*   maskp      = (const int*)d_in[2];
    const float* pts        = (const float*)d_in[3];
    const float* ray_d      = (const float*)d_in[4];
    const float* rgbfeat_w1 = (const float*)d_in[5];
    const float* rgbfeat_b1 = (const float*)d_in[6];
    const float* rgbfeat_w2 = (const float*)d_in[7];
    const float* rgbfeat_b2 = (const float*)d_in[8];
    const float* c_ln_g = (const float*)d_in[9];
    const float* c_ln_b = (const float*)d_in[10];
    const float* c_qw   = (const float*)d_in[11];
    const float* c_kw   = (const float*)d_in[12];
    const float* c_vw   = (const float*)d_in[13];
    const float* c_pw1  = (const float*)d_in[14];
    const float* c_pb1  = (const float*)d_in[15];
    const float* c_pw2  = (const float*)d_in[16];
    const float* c_pb2  = (const float*)d_in[17];
    const float* c_aw1  = (const float*)d_in[18];
    const float* c_ab1  = (const float*)d_in[19];
    const float* c_aw2  = (const float*)d_in[20];
    const float* c_ab2  = (const float*)d_in[21];
    const float* c_ow   = (const float*)d_in[22];
    const float* c_ob   = (const float*)d_in[23];
    const float* c_fg   = (const float*)d_in[24];
    const float* c_fb   = (const float*)d_in[25];
    const float* c_fw1  = (const float*)d_in[26];
    const float* c_fb1  = (const float*)d_in[27];
    const float* c_fw2  = (const float*)d_in[28];
    const float* c_fb2  = (const float*)d_in[29];
    const float* s_ln_g = (const float*)d_in[30];
    const float* s_ln_b = (const float*)d_in[31];
    const float* s_qw   = (const float*)d_in[32];
    const float* s_kw   = (const float*)d_in[33];
    const float* s_vw   = (const float*)d_in[34];
    const float* s_ow   = (const float*)d_in[35];
    const float* s_ob   = (const float*)d_in[36];
    const float* s_fg   = (const float*)d_in[37];
    const float* s_fb   = (const float*)d_in[38];
    const float* s_fw1  = (const float*)d_in[39];
    const float* s_fb1  = (const float*)d_in[40];
    const float* s_fw2  = (const float*)d_in[41];
    const float* s_fb2  = (const float*)d_in[42];
    const float* q_w1   = (const float*)d_in[43];
    const float* q_b1   = (const float*)d_in[44];
    const float* q_w2   = (const float*)d_in[45];
    const float* q_b2   = (const float*)d_in[46];
    const float* norm_g = (const float*)d_in[47];
    const float* norm_b = (const float*)d_in[48];
    const float* out_w  = (const float*)d_in[49];
    const float* out_b  = (const float*)d_in[50];
    float* out = (float*)d_out;

    // ---- workspace carve (256B aligned) ----
    char* p = (char*)d_ws;
    auto alloc = [&](size_t bytes) { char* r = p; p += (bytes + 255) & ~(size_t)255; return r; };
    short* rgbf  = (short*)alloc((size_t)BSV * 256 * 2);
    short* hall  = (short*)alloc((size_t)DD * BSV * 32 * 2);
    short* a_in  = (short*)alloc((size_t)BSV * 256 * 2);
    short* obb   = (short*)alloc((size_t)BS * 256 * 2);
    short* xq    = (short*)alloc((size_t)BS * 256 * 2);
    short* hb    = (short*)alloc((size_t)BS * 256 * 2);
    short* catb  = (short*)alloc((size_t)BS * 384 * 2);
    short* qkv   = (short*)alloc((size_t)BS * 768 * 2);
    short* rgbp  = qkv;
    float* qf    = (float*)alloc((size_t)BS * 256 * 4);
    float* fq    = (float*)alloc((size_t)BS * 256 * 4);
    // weights
    short* w1T   = (short*)alloc(256 * 64 * 2);
    short* w2T   = (short*)alloc(256 * 256 * 2);
    short* qwT   = (short*)alloc((size_t)DD * 256 * 256 * 2);
    short* kvpT  = (short*)alloc((size_t)DD * 512 * 288 * 2);
    short* aw1T  = (short*)alloc((size_t)DD * 32 * 256 * 2);
    short* aw2T  = (short*)alloc((size_t)DD * 256 * 32 * 2);
    short* owT   = (short*)alloc((size_t)DD * 256 * 256 * 2);
    short* fw1T  = (short*)alloc((size_t)DD * 1024 * 256 * 2);
    short* fw2T  = (short*)alloc((size_t)DD * 256 * 1024 * 2);
    short* sqkvT = (short*)alloc((size_t)DD * 768 * 256 * 2);
    short* sowT  = (short*)alloc((size_t)DD * 256 * 256 * 2);
    short* sfw1T = (short*)alloc((size_t)DD * 1024 * 256 * 2);
    short* sfw2T = (short*)alloc((size_t)DD * 256 * 1024 * 2);
    short* qw1T  = (short*)alloc((size_t)4 * 256 * 384 * 2);
    short* qw2T  = (short*)alloc((size_t)4 * 256 * 256 * 2);

    // ---- batched weight conversion (one dispatch) ----
    WJobs wj; int nj = 0, totblk = 0;
    // frag=0 (row-major [N,Kpad]), frag=1 (fragment-packed; KS/ntoff/ksoff)
    auto addj = [&](const float* s, short* d, int K, int N, int frag,
                    int KS, int ntoff, int ksoff, int Kpad,
                    int zi, size_t zo, int nz) {
        WJob& J = wj.j[nj++];
        J.src = s; J.dst = d; J.K = K; J.N = N; J.frag = frag;
        J.KS = KS; J.ntoff = ntoff; J.ksoff = ksoff; J.Kpad = Kpad;
        J.zi = zi; J.zo = zo; J.gy = (K + 31) >> 5;
        J.nblk = (N >> 5) * J.gy * nz;
        totblk += J.nblk;
    };
    addj(rgbfeat_w1, w1T, 35, 256, 0, 0, 0, 0, 64, 0, 0, 1);
    addj(rgbfeat_w2, w2T, 256, 256, 0, 0, 0, 0, 256, 0, 0, 1);
    addj(c_qw,  qwT,  256, 256, 1, 8, 0, 0, 0, 65536, 65536, DD);
    addj(c_kw,  kvpT, 256, 256, 1, 9, 0, 0, 0, 65536, 147456, DD);
    addj(c_pw2, kvpT, 32, 256, 1, 9, 0, 8, 0, 8192, 147456, DD);
    addj(c_vw,  kvpT, 256, 256, 1, 9, 16, 0, 0, 65536, 147456, DD);
    addj(c_pw2, kvpT, 32, 256, 1, 9, 16, 8, 0, 8192, 147456, DD);
    addj(c_aw1, aw1T, 256, 32, 1, 8, 0, 0, 0, 8192, 8192, DD);
    addj(c_aw2, aw2T, 32, 256, 1, 1, 0, 0, 0, 8192, 8192, DD);
    addj(c_ow,  owT,  256, 256, 1, 8, 0, 0, 0, 65536, 65536, DD);
    addj(c_fw1, fw1T, 256, 1024, 1, 8, 0, 0, 0, 262144, 262144, DD);
    addj(c_fw2, fw2T, 1024, 256, 1, 32, 0, 0, 0, 262144, 262144, DD);
    addj(s_qw,  sqkvT, 256, 256, 1, 8, 0, 0, 0, 65536, 196608, DD);
    addj(s_kw,  sqkvT, 256, 256, 1, 8, 16, 0, 0, 65536, 196608, DD);
    addj(s_vw,  sqkvT, 256, 256, 1, 8, 32, 0, 0, 65536, 196608, DD);
    addj(s_ow,  sowT,  256, 256, 1, 8, 0, 0, 0, 65536, 65536, DD);
    addj(s_fw1, sfw1T, 256, 1024, 1, 8, 0, 0, 0, 262144, 262144, DD);
    addj(s_fw2, sfw2T, 1024, 256, 1, 32, 0, 0, 0, 262144, 262144, DD);
    addj(q_w1,  qw1T, 346, 256, 1, 12, 0, 0, 0, 88576, 98304, 4);
    addj(q_w2,  qw2T, 256, 256, 1, 8, 0, 0, 0, 65536, 65536, 4);
    wconv_all<<<totblk, dim3(32, 8), 0, stream>>>(wj);

    // ---- preamble ----
    catpenc<<<(BS * 128) / 256, 256, 0, stream>>>(pts, ray_d, catb);
    rgbhall<<<(BSV * 64 + DD * BSV * 32) / 256, 256, 0, stream>>>(
        rgb_feat, ray_diff, c_pw1, c_pb1, rgbp, hall);
    GEMM_BF(128, 128, 64, 64, rgbp, w1T, rgbfeat_b1, a_in, BSV, 256, 64, 256, 1);
    GEMM_BF(128, 128, 64, 64, a_in, w2T, rgbfeat_b2, rgbf, BSV, 256, 256, 256, 0);
    vmaxln<<<BS, 256, 0, stream>>>(rgbf, c_ln_g, c_ln_b, fq, xq);
    qgemm0<<<256, 256, 0, stream>>>(xq, qwT, qf);

    for (int i = 0; i < DD; i++) {
        int j = i >> 1;
        crosskv<<<BSV / 32, 256, 0, stream>>>(
            rgbf, hall + (size_t)i * BSV * 32, kvpT + (size_t)i * 147456,
            qf, maskp,
            aw1T + (size_t)i * 8192, c_ab1 + i * 32,
            aw2T + (size_t)i * 8192, c_ab2 + i * 256, obb);
        chainA<<<256, 512, 0, stream>>>(obb, fq, catb, qkv,
            owT + (size_t)i * 65536, c_ob + i * 256, c_fg + i * 256, c_fb + i * 256,
            fw1T + (size_t)i * 262144, c_fb1 + i * 1024,
            fw2T + (size_t)i * 262144, c_fb2 + i * 256,
            qw1T + (size_t)j * 98304, q_b1 + j * 256,
            qw2T + (size_t)j * 65536, q_b2 + j * 256,
            s_ln_g + i * 256, s_ln_b + i * 256,
            sqkvT + (size_t)i * 196608, !(i & 1));
        attn_mfma<<<BB * 4, 256, 0, stream>>>(qkv, obb);
        int last = (i == DD - 1);
        chainB<<<256, 512, 0, stream>>>(obb, fq,
            sowT + (size_t)i * 65536, s_ob + i * 256, s_fg + i * 256, s_fb + i * 256,
            sfw1T + (size_t)i * 262144, s_fb1 + i * 1024,
            sfw2T + (size_t)i * 262144, s_fb2 + i * 256,
            last ? norm_g : c_ln_g + (i + 1) * 256,
            last ? norm_b : c_ln_b + (i + 1) * 256,
            last ? 1e-5f : 1e-6f,
            last ? nullptr : qwT + (size_t)(i + 1) * 65536,
            qf, last ? hb : nullptr);
    }

    headk<<<BB, 256, 0, stream>>>(hb, out_w, out_b, out);
}

// Round 8
// 856.995 us; speedup vs baseline: 1.0304x; 1.0122x over previous
//
#include <hip/hip_runtime.h>
#include <hip/hip_bf16.h>
#include <math.h>

#define BB 64
#define SS 64
#define VV 8
#define WW 256
#define DD 8
#define BS (BB*SS)        // 4096
#define BSV (BB*SS*VV)    // 32768

#define RB 392            // rowbuf stride (shorts)
#define HBs 1064          // hid stride
#define TB 264            // tmpb stride
#define AS 296            // crosskv A stride

typedef __attribute__((ext_vector_type(8))) short s8v;
typedef __attribute__((ext_vector_type(4))) float f4v;

__device__ __forceinline__ short f2b(float f) {
    __hip_bfloat16 h = __float2bfloat16(f);
    return *reinterpret_cast<short*>(&h);
}
__device__ __forceinline__ float b2f(short s) {
    __hip_bfloat16 h = *reinterpret_cast<__hip_bfloat16*>(&s);
    return __bfloat162float(h);
}

// ---------------------------------------------------------------------------
// B fragments are FRAGMENT-PACKED: bF[(k*64+lane)*8] -> one contiguous 1KB
// burst per wave per MFMA.
// rowgemm: generic (loads B inline), dual accumulator to halve the dependent
// MFMA chain. rowgemm_pre: B pre-loaded into registers (prefetched across a
// barrier). rowgemm_mix: first 8 k-steps prefetched, remainder streamed.
// ---------------------------------------------------------------------------
__device__ __forceinline__ void bload8(const short* __restrict__ bF, int lane,
                                       s8v* __restrict__ dst)
{
#pragma unroll
    for (int k = 0; k < 8; k++)
        dst[k] = *(const s8v*)&bF[(size_t)(k * 64 + lane) * 8];
}

__device__ __forceinline__ f4v rowgemm(const short* __restrict__ aL, int lda,
                                       const short* __restrict__ bF,
                                       int ksteps, int lane)
{
    int lm = lane & 15, lq = lane >> 4;
    f4v a0 = (f4v){0.f, 0.f, 0.f, 0.f};
    f4v a1 = (f4v){0.f, 0.f, 0.f, 0.f};
    int k = 0;
#pragma unroll 8
    for (; k + 1 < ksteps; k += 2) {
        s8v x0 = *(const s8v*)&aL[lm * lda + k * 32 + lq * 8];
        s8v b0 = *(const s8v*)&bF[(size_t)(k * 64 + lane) * 8];
        s8v x1 = *(const s8v*)&aL[lm * lda + (k + 1) * 32 + lq * 8];
        s8v b1 = *(const s8v*)&bF[(size_t)((k + 1) * 64 + lane) * 8];
        a0 = __builtin_amdgcn_mfma_f32_16x16x32_bf16(x0, b0, a0, 0, 0, 0);
        a1 = __builtin_amdgcn_mfma_f32_16x16x32_bf16(x1, b1, a1, 0, 0, 0);
    }
    if (k < ksteps) {
        s8v x = *(const s8v*)&aL[lm * lda + k * 32 + lq * 8];
        s8v b = *(const s8v*)&bF[(size_t)(k * 64 + lane) * 8];
        a0 = __builtin_amdgcn_mfma_f32_16x16x32_bf16(x, b, a0, 0, 0, 0);
    }
    return a0 + a1;
}

__device__ __forceinline__ f4v rowgemm_pre(const short* __restrict__ aL, int lda,
                                           const s8v* __restrict__ bp, int lane)
{
    int lm = lane & 15, lq = lane >> 4;
    f4v a0 = (f4v){0.f, 0.f, 0.f, 0.f};
    f4v a1 = (f4v){0.f, 0.f, 0.f, 0.f};
#pragma unroll
    for (int k = 0; k < 8; k += 2) {
        s8v x0 = *(const s8v*)&aL[lm * lda + k * 32 + lq * 8];
        s8v x1 = *(const s8v*)&aL[lm * lda + (k + 1) * 32 + lq * 8];
        a0 = __builtin_amdgcn_mfma_f32_16x16x32_bf16(x0, bp[k], a0, 0, 0, 0);
        a1 = __builtin_amdgcn_mfma_f32_16x16x32_bf16(x1, bp[k + 1], a1, 0, 0, 0);
    }
    return a0 + a1;
}

__device__ __forceinline__ f4v rowgemm_mix(const short* __restrict__ aL, int lda,
                                           const s8v* __restrict__ bp,
                                           const short* __restrict__ bF,
                                           int ksteps, int lane)
{
    int lm = lane & 15, lq = lane >> 4;
    f4v a0 = (f4v){0.f, 0.f, 0.f, 0.f};
    f4v a1 = (f4v){0.f, 0.f, 0.f, 0.f};
#pragma unroll
    for (int k = 0; k < 8; k += 2) {
        s8v x0 = *(const s8v*)&aL[lm * lda + k * 32 + lq * 8];
        s8v x1 = *(const s8v*)&aL[lm * lda + (k + 1) * 32 + lq * 8];
        a0 = __builtin_amdgcn_mfma_f32_16x16x32_bf16(x0, bp[k], a0, 0, 0, 0);
        a1 = __builtin_amdgcn_mfma_f32_16x16x32_bf16(x1, bp[k + 1], a1, 0, 0, 0);
    }
#pragma unroll 8
    for (int k = 8; k + 1 < ksteps; k += 2) {
        s8v x0 = *(const s8v*)&aL[lm * lda + k * 32 + lq * 8];
        s8v b0 = *(const s8v*)&bF[(size_t)(k * 64 + lane) * 8];
        s8v x1 = *(const s8v*)&aL[lm * lda + (k + 1) * 32 + lq * 8];
        s8v b1 = *(const s8v*)&bF[(size_t)((k + 1) * 64 + lane) * 8];
        a0 = __builtin_amdgcn_mfma_f32_16x16x32_bf16(x0, b0, a0, 0, 0, 0);
        a1 = __builtin_amdgcn_mfma_f32_16x16x32_bf16(x1, b1, a1, 0, 0, 0);
    }
    return a0 + a1;
}

// ---------------------------------------------------------------------------
// In-block LayerNorm of 16 rows x 256 cols held in registers v[t][r].
// Fused-moment version (var = E[x^2]-mean^2): 2 barriers instead of 4.
// 8-wave: each wave owns 2 column-tiles (32 cols). red = 256 floats.
// ---------------------------------------------------------------------------
__device__ __forceinline__ void ln_rows(
    float v[2][4], const float* __restrict__ g, const float* __restrict__ b,
    float eps, short* rowbuf, float* red, int w, int lm, int lq,
    short* __restrict__ outG, int row0)
{
    float ps[4], pq[4];
#pragma unroll
    for (int r = 0; r < 4; r++) {
        ps[r] = v[0][r] + v[1][r];
        pq[r] = v[0][r] * v[0][r] + v[1][r] * v[1][r];
    }
#pragma unroll
    for (int m = 1; m < 16; m <<= 1)
#pragma unroll
        for (int r = 0; r < 4; r++) {
            ps[r] += __shfl_xor(ps[r], m);
            pq[r] += __shfl_xor(pq[r], m);
        }
    if (lm == 0)
#pragma unroll
        for (int r = 0; r < 4; r++) {
            red[(lq * 4 + r) * 16 + w] = ps[r];
            red[(lq * 4 + r) * 16 + 8 + w] = pq[r];
        }
    __syncthreads();
    float mean[4], inv[4];
#pragma unroll
    for (int r = 0; r < 4; r++) {
        int row = lq * 4 + r;
        float s = 0.f, s2 = 0.f;
#pragma unroll
        for (int q = 0; q < 8; q++) { s += red[row * 16 + q]; s2 += red[row * 16 + 8 + q]; }
        mean[r] = s * (1.f / 256.f);
        float var = fmaxf(s2 * (1.f / 256.f) - mean[r] * mean[r], 0.f);
        inv[r] = rsqrtf(var + eps);
    }
#pragma unroll
    for (int t = 0; t < 2; t++) {
        int col = (w * 2 + t) * 16 + lm;
        float gc = g[col], bc = b[col];
#pragma unroll
        for (int r = 0; r < 4; r++) {
            float val = (v[t][r] - mean[r]) * inv[r] * gc + bc;
            rowbuf[(lq * 4 + r) * RB + col] = f2b(val);
            if (outG) outG[(size_t)(row0 + lq * 4 + r) * 256 + col] = f2b(val);
        }
    }
    __syncthreads();
}

// ---------------------------------------------------------------------------
// chainA: ow+res -> LN(c_fg) -> fw1 -> fw2+res -> [even: cat->q1->q2]
//         -> write fq -> LN(s_ln) -> sqkv.  Block = 16 rows, 512 thr, grid 256.
// B-fragment loads for each phase are prefetched into registers BEFORE the
// preceding barrier so the L2 latency hides under LN/staging barriers.
// ---------------------------------------------------------------------------
__global__ __launch_bounds__(512) void chainA(
    const short* __restrict__ obb, float* __restrict__ fq,
    const short* __restrict__ catb, short* __restrict__ qkv,
    const short* __restrict__ owT, const float* __restrict__ c_ob,
    const float* __restrict__ c_fg, const float* __restrict__ c_fb,
    const short* __restrict__ fw1T, const float* __restrict__ c_fb1,
    const short* __restrict__ fw2T, const float* __restrict__ c_fb2,
    const short* __restrict__ qw1T, const float* __restrict__ q_b1,
    const short* __restrict__ qw2T, const float* __restrict__ q_b2,
    const float* __restrict__ s_ln_g, const float* __restrict__ s_ln_b,
    const short* __restrict__ sqkvT, int even)
{
    __shared__ __align__(16) short rowbuf[16 * RB];
    __shared__ __align__(16) short hid[16 * HBs];
    __shared__ __align__(16) short tmpb[16 * TB];
    __shared__ float red[256];
    int tid = threadIdx.x, lane = tid & 63, w = tid >> 6;  // w in [0,8)
    int lm = lane & 15, lq = lane >> 4;
    int row0 = blockIdx.x * 16;
    // prefetch ow B-fragments (overlaps obb staging + barrier)
    s8v bo[16];
    bload8(owT + (size_t)(w * 2 + 0) * 4096, lane, bo);
    bload8(owT + (size_t)(w * 2 + 1) * 4096, lane, bo + 8);
    {
        int r = tid >> 5, c = (tid & 31) * 8;
        *(s8v*)&rowbuf[r * RB + c] = *(const s8v*)&obb[(size_t)(row0 + r) * 256 + c];
    }
    __syncthreads();
    float fqreg[2][4];
#pragma unroll
    for (int t = 0; t < 2; t++) {
        f4v o = rowgemm_pre(rowbuf, RB, bo + t * 8, lane);
        int col = (w * 2 + t) * 16 + lm;
        float bb = c_ob[col];
#pragma unroll
        for (int r = 0; r < 4; r++)
            fqreg[t][r] = o[r] + bb + fq[(size_t)(row0 + lq * 4 + r) * 256 + col];
    }
    // prefetch fw1 tiles 0,1 (overlaps the LN barriers)
    s8v bf[16];
    bload8(fw1T + (size_t)(w * 8 + 0) * 4096, lane, bf);
    bload8(fw1T + (size_t)(w * 8 + 1) * 4096, lane, bf + 8);
    ln_rows(fqreg, c_fg, c_fb, 1e-6f, rowbuf, red, w, lm, lq, nullptr, row0);
#pragma unroll
    for (int t = 0; t < 8; t++) {
        f4v o = (t < 2) ? rowgemm_pre(rowbuf, RB, bf + t * 8, lane)
                        : rowgemm(rowbuf, RB, fw1T + (size_t)(w * 8 + t) * 4096, 8, lane);
        int col = (w * 8 + t) * 16 + lm;
        float bb = c_fb1[col];
#pragma unroll
        for (int r = 0; r < 4; r++)
            hid[(lq * 4 + r) * HBs + col] = f2b(fmaxf(o[r] + bb, 0.f));
    }
    // prefetch fw2 first 8 k-steps of both tiles (overlaps hid barrier)
    s8v b2[16];
    bload8(fw2T + (size_t)(w * 2 + 0) * 16384, lane, b2);
    bload8(fw2T + (size_t)(w * 2 + 1) * 16384, lane, b2 + 8);
    __syncthreads();
#pragma unroll
    for (int t = 0; t < 2; t++) {
        f4v o = rowgemm_mix(hid, HBs, b2 + t * 8,
                            fw2T + (size_t)(w * 2 + t) * 16384, 32, lane);
        int col = (w * 2 + t) * 16 + lm;
        float bb = c_fb2[col];
#pragma unroll
        for (int r = 0; r < 4; r++)
            fqreg[t][r] = o[r] + bb + fqreg[t][r];
    }
    if (even) {
#pragma unroll
        for (int t = 0; t < 2; t++) {
            int col = (w * 2 + t) * 16 + lm;
#pragma unroll
            for (int r = 0; r < 4; r++)
                rowbuf[(lq * 4 + r) * RB + col] = f2b(fqreg[t][r]);
        }
        if (tid < 256) {
            int r = tid >> 4, c = (tid & 15) * 8;
            *(s8v*)&rowbuf[r * RB + 256 + c] = *(const s8v*)&catb[(size_t)(row0 + r) * 384 + 256 + c];
        }
        // prefetch q1 first 8 k-steps of both tiles (overlaps barrier)
        s8v bq[16];
        bload8(qw1T + (size_t)(w * 2 + 0) * 6144, lane, bq);
        bload8(qw1T + (size_t)(w * 2 + 1) * 6144, lane, bq + 8);
        __syncthreads();
#pragma unroll
        for (int t = 0; t < 2; t++) {
            f4v o = rowgemm_mix(rowbuf, RB, bq + t * 8,
                                qw1T + (size_t)(w * 2 + t) * 6144, 12, lane);
            int col = (w * 2 + t) * 16 + lm;
            float bb = q_b1[col];
#pragma unroll
            for (int r = 0; r < 4; r++)
                tmpb[(lq * 4 + r) * TB + col] = f2b(fmaxf(o[r] + bb, 0.f));
        }
        // prefetch q2 (full, both tiles) across the tmpb barrier
        s8v bq2[16];
        bload8(qw2T + (size_t)(w * 2 + 0) * 4096, lane, bq2);
        bload8(qw2T + (size_t)(w * 2 + 1) * 4096, lane, bq2 + 8);
        __syncthreads();
#pragma unroll
        for (int t = 0; t < 2; t++) {
            f4v o = rowgemm_pre(tmpb, TB, bq2 + t * 8, lane);
            int col = (w * 2 + t) * 16 + lm;
            float bb = q_b2[col];
#pragma unroll
            for (int r = 0; r < 4; r++)
                fqreg[t][r] = o[r] + bb;
        }
    }
#pragma unroll
    for (int t = 0; t < 2; t++) {
        int col = (w * 2 + t) * 16 + lm;
#pragma unroll
        for (int r = 0; r < 4; r++)
            fq[(size_t)(row0 + lq * 4 + r) * 256 + col] = fqreg[t][r];
    }
    // prefetch sqkv tiles 0,1 (overlaps the LN barriers)
    s8v bs[16];
    bload8(sqkvT + (size_t)(w * 6 + 0) * 4096, lane, bs);
    bload8(sqkvT + (size_t)(w * 6 + 1) * 4096, lane, bs + 8);
    ln_rows(fqreg, s_ln_g, s_ln_b, 1e-6f, rowbuf, red, w, lm, lq, nullptr, row0);
#pragma unroll
    for (int t = 0; t < 6; t++) {
        f4v o = (t < 2) ? rowgemm_pre(rowbuf, RB, bs + t * 8, lane)
                        : rowgemm(rowbuf, RB, sqkvT + (size_t)(w * 6 + t) * 4096, 8, lane);
        int col = (w * 6 + t) * 16 + lm;
#pragma unroll
        for (int r = 0; r < 4; r++)
            qkv[(size_t)(row0 + lq * 4 + r) * 768 + col] = f2b(o[r]);
    }
}

// ---------------------------------------------------------------------------
// chainB: sow+res -> LN(s_fg) -> sfw1 -> sfw2+res -> write fq ->
//         LN(next c_ln | final norm[->hb]) -> qw_next -> qf.  512 threads.
// Same cross-barrier B-prefetch structure as chainA.
// ---------------------------------------------------------------------------
__global__ __launch_bounds__(512) void chainB(
    const short* __restrict__ obb, float* __restrict__ fq,
    const short* __restrict__ sowT, const float* __restrict__ s_ob,
    const float* __restrict__ s_fg, const float* __restrict__ s_fb,
    const short* __restrict__ sfw1T, const float* __restrict__ s_fb1,
    const short* __restrict__ sfw2T, const float* __restrict__ s_fb2,
    const float* __restrict__ ln2_g, const float* __restrict__ ln2_b, float eps2,
    const short* __restrict__ qwTn, float* __restrict__ qf,
    short* __restrict__ hbG)
{
    __shared__ __align__(16) short rowbuf[16 * RB];
    __shared__ __align__(16) short hid[16 * HBs];
    __shared__ float red[256];
    int tid = threadIdx.x, lane = tid & 63, w = tid >> 6;
    int lm = lane & 15, lq = lane >> 4;
    int row0 = blockIdx.x * 16;
    s8v bo[16];
    bload8(sowT + (size_t)(w * 2 + 0) * 4096, lane, bo);
    bload8(sowT + (size_t)(w * 2 + 1) * 4096, lane, bo + 8);
    {
        int r = tid >> 5, c = (tid & 31) * 8;
        *(s8v*)&rowbuf[r * RB + c] = *(const s8v*)&obb[(size_t)(row0 + r) * 256 + c];
    }
    __syncthreads();
    float fqreg[2][4];
#pragma unroll
    for (int t = 0; t < 2; t++) {
        f4v o = rowgemm_pre(rowbuf, RB, bo + t * 8, lane);
        int col = (w * 2 + t) * 16 + lm;
        float bb = s_ob[col];
#pragma unroll
        for (int r = 0; r < 4; r++)
            fqreg[t][r] = o[r] + bb + fq[(size_t)(row0 + lq * 4 + r) * 256 + col];
    }
    s8v bf[16];
    bload8(sfw1T + (size_t)(w * 8 + 0) * 4096, lane, bf);
    bload8(sfw1T + (size_t)(w * 8 + 1) * 4096, lane, bf + 8);
    ln_rows(fqreg, s_fg, s_fb, 1e-6f, rowbuf, red, w, lm, lq, nullptr, row0);
#pragma unroll
    for (int t = 0; t < 8; t++) {
        f4v o = (t < 2) ? rowgemm_pre(rowbuf, RB, bf + t * 8, lane)
                        : rowgemm(rowbuf, RB, sfw1T + (size_t)(w * 8 + t) * 4096, 8, lane);
        int col = (w * 8 + t) * 16 + lm;
        float bb = s_fb1[col];
#pragma unroll
        for (int r = 0; r < 4; r++)
            hid[(lq * 4 + r) * HBs + col] = f2b(fmaxf(o[r] + bb, 0.f));
    }
    s8v b2[16];
    bload8(sfw2T + (size_t)(w * 2 + 0) * 16384, lane, b2);
    bload8(sfw2T + (size_t)(w * 2 + 1) * 16384, lane, b2 + 8);
    __syncthreads();
#pragma unroll
    for (int t = 0; t < 2; t++) {
        f4v o = rowgemm_mix(hid, HBs, b2 + t * 8,
                            sfw2T + (size_t)(w * 2 + t) * 16384, 32, lane);
        int col = (w * 2 + t) * 16 + lm;
        float bb = s_fb2[col];
#pragma unroll
        for (int r = 0; r < 4; r++)
            fqreg[t][r] = o[r] + bb + fqreg[t][r];
    }
#pragma unroll
    for (int t = 0; t < 2; t++) {
        int col = (w * 2 + t) * 16 + lm;
#pragma unroll
        for (int r = 0; r < 4; r++)
            fq[(size_t)(row0 + lq * 4 + r) * 256 + col] = fqreg[t][r];
    }
    s8v bq[16];
    if (qwTn) {
        bload8(qwTn + (size_t)(w * 2 + 0) * 4096, lane, bq);
        bload8(qwTn + (size_t)(w * 2 + 1) * 4096, lane, bq + 8);
    }
    ln_rows(fqreg, ln2_g, ln2_b, eps2, rowbuf, red, w, lm, lq, hbG, row0);
    if (qwTn) {
#pragma unroll
        for (int t = 0; t < 2; t++) {
            f4v o = rowgemm_pre(rowbuf, RB, bq + t * 8, lane);
            int col = (w * 2 + t) * 16 + lm;
#pragma unroll
            for (int r = 0; r < 4; r++)
                qf[(size_t)(row0 + lq * 4 + r) * 256 + col] = o[r];
        }
    }
}

// layer-0 q projection: qf = xq @ qw0 (frag-packed), block = 16 rows
__global__ __launch_bounds__(256) void qgemm0(
    const short* __restrict__ xq, const short* __restrict__ qwT0,
    float* __restrict__ qf)
{
    __shared__ __align__(16) short rowbuf[16 * TB];
    int tid = threadIdx.x, lane = tid & 63, w = tid >> 6;
    int lm = lane & 15, lq = lane >> 4;
    int row0 = blockIdx.x * 16;
    {
        int r = tid >> 4, c = (tid & 15) * 16;
        *(s8v*)&rowbuf[r * TB + c]     = *(const s8v*)&xq[(size_t)(row0 + r) * 256 + c];
        *(s8v*)&rowbuf[r * TB + c + 8] = *(const s8v*)&xq[(size_t)(row0 + r) * 256 + c + 8];
    }
    __syncthreads();
#pragma unroll
    for (int t = 0; t < 4; t++) {
        f4v o = rowgemm(rowbuf, TB, qwT0 + (size_t)(w * 4 + t) * 4096, 8, lane);
        int col = (w * 4 + t) * 16 + lm;
#pragma unroll
        for (int r = 0; r < 4; r++)
            qf[(size_t)(row0 + lq * 4 + r) * 256 + col] = o[r];
    }
}

// ---------------------------------------------------------------------------
// crosskv: fused kv-projection + cross-attention. Block = 64 kv rows
// (8 samples), 512 threads, grid 512. Halves per-row kvp B-traffic vs the
// 32-row version (each B ntile amortizes over 4 row-tiles) at identical
// waves/CU (2 blocks x 8 waves vs 4 x 4; LDS 77 KB).
// ---------------------------------------------------------------------------
__global__ __launch_bounds__(512) void crosskv(
    const short* __restrict__ rgbf, const short* __restrict__ hall_l,
    const short* __restrict__ kvpT_l, const float* __restrict__ qf,
    const int* __restrict__ mask,
    const short* __restrict__ aw1T_l, const float* __restrict__ ab1,
    const short* __restrict__ aw2T_l, const float* __restrict__ ab2,
    short* __restrict__ obb)
{
    __shared__ __align__(16) short A_s[64 * AS];
    __shared__ __align__(16) short a_s[64 * 264];
    __shared__ __align__(16) short ph_s[64 * 40];
    __shared__ int msk[64];
    int blk = blockIdx.x, tid = threadIdx.x;
    int row0 = blk * 64, bs0 = blk * 8;
    int lane = tid & 63, w = tid >> 6, lm = lane & 15, lq = lane >> 4;  // w in [0,8)
    if (tid < 64) msk[tid] = mask[bs0 * 8 + tid];
#pragma unroll
    for (int i = 0; i < 4; i++) {
        int e = tid + i * 512;
        int r = e >> 5, c = (e & 31) << 3;
        *(s8v*)&A_s[r * AS + c] = *(const s8v*)&rgbf[(size_t)(row0 + r) * 256 + c];
    }
    if (tid < 256) {
        int r = tid >> 2, c = (tid & 3) << 3;
        *(s8v*)&A_s[r * AS + 256 + c] = *(const s8v*)&hall_l[(size_t)(row0 + r) * 32 + c];
    }
    __syncthreads();
    // k-half: each wave handles ntiles w*2+{0,1}; B reused across 4 row-tiles
#pragma unroll
    for (int j2 = 0; j2 < 2; j2++) {
        int nt = w * 2 + j2;
#pragma unroll
        for (int i = 0; i < 4; i++) {
            f4v acc = rowgemm(&A_s[i * 16 * AS], AS, kvpT_l + (size_t)nt * 9 * 512, 9, lane);
#pragma unroll
            for (int r = 0; r < 4; r++) {
                int row = i * 16 + lq * 4 + r, col = nt * 16 + lm;
                float q = qf[(size_t)(bs0 + (row >> 3)) * 256 + col];
                a_s[row * 264 + col] = f2b(acc[r] - q);
            }
        }
    }
    __syncthreads();
    // ph = relu(a_in @ aw1 + ab1): 64 rows x 32 cols = 8 tiles of 16x16
    {
        int i = w >> 1, j = w & 1;
        f4v acc = rowgemm(&a_s[i * 16 * 264], 264, aw1T_l + (size_t)j * 4096, 8, lane);
        int col = j * 16 + lm;
        float bb = ab1[col];
#pragma unroll
        for (int r = 0; r < 4; r++)
            ph_s[(i * 16 + lq * 4 + r) * 40 + col] = f2b(fmaxf(acc[r] + bb, 0.f));
    }
    __syncthreads();
    // a3 = ph @ aw2 (KS=1): per wave, ntiles w*2+j2, 4 row-tiles
    f4v a3[4][2];
#pragma unroll
    for (int i = 0; i < 4; i++) {
#pragma unroll
        for (int j2 = 0; j2 < 2; j2++) {
            int nt = w * 2 + j2;
            a3[i][j2] = rowgemm(&ph_s[i * 16 * 40], 40, aw2T_l + (size_t)nt * 512, 1, lane);
        }
    }
    // v-half: same B amortization as k-half
#pragma unroll
    for (int j2 = 0; j2 < 2; j2++) {
        int nt = w * 2 + j2;
#pragma unroll
        for (int i = 0; i < 4; i++) {
            f4v acc = rowgemm(&A_s[i * 16 * AS], AS, kvpT_l + (size_t)(16 + nt) * 9 * 512, 9, lane);
#pragma unroll
            for (int r = 0; r < 4; r++)
                a_s[(i * 16 + lq * 4 + r) * 264 + nt * 16 + lm] = f2b(acc[r]);
        }
    }
    __syncthreads();
    // masked softmax over views + weighted sum (each wave: its 2 col-tiles,
    // all 64 rows = 8 samples)
#pragma unroll
    for (int i = 0; i < 4; i++) {
        int sample = i * 2 + (lq >> 1);
        int mk[4];
#pragma unroll
        for (int r = 0; r < 4; r++) mk[r] = msk[sample * 8 + (lq & 1) * 4 + r];
#pragma unroll
        for (int j2 = 0; j2 < 2; j2++) {
            int col = (w * 2 + j2) * 16 + lm;
            float bv = ab2[col];
            float vals[4];
#pragma unroll
            for (int r = 0; r < 4; r++) vals[r] = mk[r] ? (a3[i][j2][r] + bv) : -1e9f;
            float mx = fmaxf(fmaxf(vals[0], vals[1]), fmaxf(vals[2], vals[3]));
            mx = fmaxf(mx, __shfl_xor(mx, 16));
            float ev[4], s = 0.f;
#pragma unroll
            for (int r = 0; r < 4; r++) { ev[r] = expf(vals[r] - mx); s += ev[r]; }
            s += __shfl_xor(s, 16);
            float o = 0.f;
#pragma unroll
            for (int r = 0; r < 4; r++)
                o += ev[r] * b2f(a_s[(i * 16 + lq * 4 + r) * 264 + col]);
            o += __shfl_xor(o, 16);
            o /= s;
            if (!(lq & 1)) obb[(size_t)(bs0 + sample) * 256 + col] = f2b(o);
        }
    }
}

// ---------------------------------------------------------------------------
// bf16 MFMA GEMM (BK=32, LDS stride 40) — preamble only (row-major B^T).
// ---------------------------------------------------------------------------
template<int TM, int TN, int WM, int WN, bool OUTBF>
__global__ __launch_bounds__(256) void gemm_mfma(
    const short* __restrict__ A, const short* __restrict__ Bt,
    const float* __restrict__ bias, const float* __restrict__ res,
    float* __restrict__ Cf, short* __restrict__ Cb,
    int M, int N, int K, int ldc, int relu)
{
    constexpr int MT  = WM / 16;
    constexpr int NT  = WN / 16;
    constexpr int RWN = TN / WN;
    __shared__ __align__(16) short As[TM * 40];
    __shared__ __align__(16) short Bs[TN * 40];
    int tid = threadIdx.x;
    int m0 = blockIdx.y * TM, n0 = blockIdx.x * TN;
    int lane = tid & 63, w = tid >> 6;
    int lm = lane & 15, lq = lane >> 4;
    int wm = (w / RWN) * WM, wn = (w % RWN) * WN;
    f4v acc[MT][NT];
#pragma unroll
    for (int i = 0; i < MT; i++)
#pragma unroll
        for (int j = 0; j < NT; j++) acc[i][j] = (f4v){0.f, 0.f, 0.f, 0.f};

    for (int k0 = 0; k0 < K; k0 += 32) {
        for (int c = tid; c < TM * 4; c += 256) {
            int r = c >> 2, kc = (c & 3) << 3;
            *(s8v*)&As[r * 40 + kc] = *(const s8v*)&A[(size_t)(m0 + r) * K + k0 + kc];
        }
        for (int c = tid; c < TN * 4; c += 256) {
            int r = c >> 2, kc = (c & 3) << 3;
            *(s8v*)&Bs[r * 40 + kc] = *(const s8v*)&Bt[(size_t)(n0 + r) * K + k0 + kc];
        }
        __syncthreads();
        s8v af[MT], bfv[NT];
#pragma unroll
        for (int i = 0; i < MT; i++)
            af[i] = *(const s8v*)&As[(wm + i * 16 + lm) * 40 + lq * 8];
#pragma unroll
        for (int j = 0; j < NT; j++)
            bfv[j] = *(const s8v*)&Bs[(wn + j * 16 + lm) * 40 + lq * 8];
#pragma unroll
        for (int i = 0; i < MT; i++)
#pragma unroll
            for (int j = 0; j < NT; j++)
                acc[i][j] = __builtin_amdgcn_mfma_f32_16x16x32_bf16(af[i], bfv[j], acc[i][j], 0, 0, 0);
        __syncthreads();
    }
#pragma unroll
    for (int i = 0; i < MT; i++) {
        int row = m0 + wm + i * 16 + lq * 4;
#pragma unroll
        for (int j = 0; j < NT; j++) {
            int col = n0 + wn + j * 16 + lm;
            float bv = bias ? bias[col] : 0.f;
#pragma unroll
            for (int r = 0; r < 4; r++) {
                float v = acc[i][j][r] + bv;
                if (relu) v = fmaxf(v, 0.f);
                size_t idx = (size_t)(row + r) * ldc + col;
                if (OUTBF) {
                    Cb[idx] = f2b(v);
                } else {
                    if (res) v += res[idx];
                    Cf[idx] = v;
                }
            }
        }
    }
}

// ---------------------------------------------------------------------------
// Batched weight convert: fp32 [K,N] -> bf16, either row-major [N,Kpad]
// (frag=0) or MFMA-fragment-packed [ntile][kstep][lane][8] (frag=1).
// ---------------------------------------------------------------------------
struct WJob {
    const float* src; short* dst;
    int K, N, KS, ntoff, ksoff, Kpad, zi, gy, nblk, frag;
    size_t zo;
};
struct WJobs { WJob j[20]; };

__global__ void wconv_all(WJobs jobs)
{
    __shared__ float t[32][33];
    int b = blockIdx.x, ji = 0;
    while (b >= jobs.j[ji].nblk) { b -= jobs.j[ji].nblk; ji++; }
    WJob J = jobs.j[ji];
    int gx = J.N >> 5;
    int z = b / (gx * J.gy);
    int rem = b - z * (gx * J.gy);
    int by = rem / gx, bx = rem - by * gx;
    const float* W = J.src + (size_t)z * J.zi;
    short* Wt = J.dst + (size_t)z * J.zo;
    int n0 = bx * 32, k0 = by * 32;
    int tx = threadIdx.x, ty = threadIdx.y;
#pragma unroll
    for (int i = 0; i < 4; i++) {
        int k = k0 + ty + i * 8;
        t[ty + i * 8][tx] = (k < J.K) ? W[(size_t)k * J.N + n0 + tx] : 0.f;
    }
    __syncthreads();
    if (J.frag) {
        if (ty < 4) {
            int n = n0 + tx;
            int nt = J.ntoff + (n >> 4), lmm = n & 15;
            int ks = J.ksoff + (k0 >> 5);
            s8v o;
#pragma unroll
            for (int jj = 0; jj < 8; jj++) o[jj] = f2b(t[ty * 8 + jj][tx]);
            *(s8v*)&Wt[(((size_t)nt * J.KS + ks) * 64 + ty * 16 + lmm) * 8] = o;
        }
    } else {
#pragma unroll
        for (int i = 0; i < 4; i++) {
            int n = n0 + ty + i * 8;
            Wt[(size_t)n * J.Kpad + k0 + tx] = f2b(t[tx][ty + i * 8]);
        }
    }
}

// catb tail computed directly from pts/ray_d (penc inline)
__global__ void catpenc(const float* __restrict__ pts, const float* __restrict__ ray_d,
                        short* __restrict__ catb)
{
    int idx = blockIdx.x * 256 + threadIdx.x;
    int bs = idx >> 7, c = idx & 127;
    float v = 0.f;
    if (c < 63) {
        if (c < 3) v = pts[bs * 3 + c];
        else {
            int e = c - 3; int d, k; bool sn;
            if (e < 30) { d = e / 10; k = e - d * 10; sn = true; }
            else { e -= 30; d = e / 10; k = e - d * 10; sn = false; }
            float ang = pts[bs * 3 + d] * (float)(1 << k);
            v = sn ? sinf(ang) : cosf(ang);
        }
    } else if (c < 90) {
        int e = c - 63, b = bs >> 6;
        float x = ray_d[b * 3], y = ray_d[b * 3 + 1], z = ray_d[b * 3 + 2];
        float inv = rsqrtf(x * x + y * y + z * z);
        float vv[3] = {x * inv, y * inv, z * inv};
        if (e < 3) v = vv[e];
        else if (e < 15) { int d = (e - 3) >> 2, k = (e - 3) & 3; v = sinf(vv[d] * (float)(1 << k)); }
        else { int d = (e - 15) >> 2, k = (e - 15) & 3; v = cosf(vv[d] * (float)(1 << k)); }
    }
    catb[(size_t)bs * 384 + 256 + c] = f2b(v);
}

// rgb_feat pad-convert + hall (all 8 layers) in one launch
__global__ void rgbhall(const float* __restrict__ rgb_feat, const float* __restrict__ rdiff,
                        const float* __restrict__ pw1, const float* __restrict__ pb1,
                        short* __restrict__ rgbp, short* __restrict__ hall)
{
    int idx = blockIdx.x * 256 + threadIdx.x;
    if (idx < BSV * 64) {
        int row = idx >> 6, col = idx & 63;
        rgbp[idx] = f2b(col < 35 ? rgb_feat[row * 35 + col] : 0.f);
    } else {
        int k = idx - BSV * 64;
        int t = k & 31, row = (k >> 5) & (BSV - 1), l = k >> 20;
        float a = pb1[l * 32 + t];
        for (int c = 0; c < 4; c++) a += rdiff[row * 4 + c] * pw1[l * 128 + c * 32 + t];
        hall[k] = f2b(fmaxf(a, 0.f));
    }
}

// view-max + layer-0 LayerNorm fused
__global__ __launch_bounds__(256) void vmaxln(
    const short* __restrict__ rgbf, const float* __restrict__ g,
    const float* __restrict__ b, float* __restrict__ fq, short* __restrict__ xq)
{
    int bs = blockIdx.x, t = threadIdx.x;
    float m = -1e30f;
    for (int v = 0; v < VV; v++) m = fmaxf(m, b2f(rgbf[((size_t)(bs * VV + v)) * 256 + t]));
    fq[(size_t)bs * WW + t] = m;
    __shared__ float red[256];
    red[t] = m;
    __syncthreads();
    for (int s = 128; s > 0; s >>= 1) { if (t < s) red[t] += red[t + s]; __syncthreads(); }
    float mean = red[0] * (1.f / 256.f);
    __syncthreads();
    float d = m - mean;
    red[t] = d * d;
    __syncthreads();
    for (int s = 128; s > 0; s >>= 1) { if (t < s) red[t] += red[t + s]; __syncthreads(); }
    float var = red[0] * (1.f / 256.f);
    xq[(size_t)bs * WW + t] = f2b(d / sqrtf(var + 1e-6f) * g[t] + b[t]);
}

// ---------------------------------------------------------------------------
// MFMA self-attention: one block per (b,h), 4 waves — each wave owns one
// 16-row query tile (softmax is row-local, so no cross-wave reduction).
// QKV packed bf16 [4096,768].
// ---------------------------------------------------------------------------
__global__ __launch_bounds__(256) void attn_mfma(
    const short* __restrict__ QKV, short* __restrict__ O)
{
    __shared__ __align__(16) short P[64 * 72];
    __shared__ __align__(16) short Vt[64 * 72];
    int blk = blockIdx.x;
    int b = blk >> 2, h = blk & 3;
    int tid = threadIdx.x, lane = tid & 63, w = tid >> 6;
    int lm = lane & 15, lq = lane >> 4;
    const short* base = QKV + (size_t)b * 64 * 768 + h * 64;
    {
        int row = tid & 63, c0 = (tid >> 6) * 2;
        const short* vrow = base + 512 + (size_t)row * 768;
#pragma unroll
        for (int c = c0; c < c0 + 2; c++) {
            s8v v = *(const s8v*)&vrow[c * 8];
#pragma unroll
            for (int j = 0; j < 8; j++)
                Vt[(c * 8 + j) * 72 + row] = v[j];
        }
    }
    s8v qfr[2], kf[4][2];
#pragma unroll
    for (int c = 0; c < 2; c++) {
        qfr[c] = *(const s8v*)&base[(size_t)(w * 16 + lm) * 768 + c * 32 + lq * 8];
#pragma unroll
        for (int j = 0; j < 4; j++)
            kf[j][c] = *(const s8v*)&base[(size_t)(j * 16 + lm) * 768 + 256 + c * 32 + lq * 8];
    }
    f4v acc[4];
#pragma unroll
    for (int j = 0; j < 4; j++) acc[j] = (f4v){0.f, 0.f, 0.f, 0.f};
#pragma unroll
    for (int c = 0; c < 2; c++)
#pragma unroll
        for (int j = 0; j < 4; j++)
            acc[j] = __builtin_amdgcn_mfma_f32_16x16x32_bf16(qfr[c], kf[j][c], acc[j], 0, 0, 0);
#pragma unroll
    for (int r = 0; r < 4; r++) {
        float lv[4];
#pragma unroll
        for (int j = 0; j < 4; j++) lv[j] = acc[j][r] * 0.125f;
        float mx = fmaxf(fmaxf(lv[0], lv[1]), fmaxf(lv[2], lv[3]));
        for (int d = 1; d < 16; d <<= 1) mx = fmaxf(mx, __shfl_xor(mx, d));
        float sum = 0.f;
#pragma unroll
        for (int j = 0; j < 4; j++) { lv[j] = expf(lv[j] - mx); sum += lv[j]; }
        for (int d = 1; d < 16; d <<= 1) sum += __shfl_xor(sum, d);
        float inv = 1.f / sum;
        int row = w * 16 + lq * 4 + r;
#pragma unroll
        for (int j = 0; j < 4; j++)
            P[row * 72 + j * 16 + lm] = f2b(lv[j] * inv);
    }
    __syncthreads();
    s8v af[2], bf[4][2];
#pragma unroll
    for (int c = 0; c < 2; c++) {
        af[c] = *(const s8v*)&P[(w * 16 + lm) * 72 + c * 32 + lq * 8];
#pragma unroll
        for (int j = 0; j < 4; j++)
            bf[j][c] = *(const s8v*)&Vt[(j * 16 + lm) * 72 + c * 32 + lq * 8];
    }
    f4v o2[4];
#pragma unroll
    for (int j = 0; j < 4; j++) o2[j] = (f4v){0.f, 0.f, 0.f, 0.f};
#pragma unroll
    for (int c = 0; c < 2; c++)
#pragma unroll
        for (int j = 0; j < 4; j++)
            o2[j] = __builtin_amdgcn_mfma_f32_16x16x32_bf16(af[c], bf[j][c], o2[j], 0, 0, 0);
#pragma unroll
    for (int j = 0; j < 4; j++)
#pragma unroll
        for (int r = 0; r < 4; r++) {
            int s = w * 16 + lq * 4 + r, d = j * 16 + lm;
            O[(size_t)(b * 64 + s) * 256 + h * 64 + d] = f2b(o2[j][r]);
        }
}

__global__ __launch_bounds__(256) void headk(
    const short* __restrict__ h, const float* __restrict__ ow,
    const float* __restrict__ ob, float* __restrict__ out)
{
    int b = blockIdx.x, t = threadIdx.x;
    float acc = 0.f;
    for (int s = 0; s < SS; s++) acc += b2f(h[((size_t)(b * SS + s)) * WW + t]);
    __shared__ float mean[256];
    mean[t] = acc * (1.f / 64.f);
    __syncthreads();
    if (t < 3) {
        float o = ob[t];
        for (int w = 0; w < WW; w++) o += mean[w] * ow[w * 3 + t];
        out[b * 3 + t] = o;
    }
}

// ---------------------------------------------------------------------------
#define GEMM_BF(TMv,TNv,WMv,WNv, A,Bt,bias,C,M,N,K,ldc,relu) \
  gemm_mfma<TMv,TNv,WMv,WNv,true><<<dim3((N)/(TNv),(M)/(TMv)),256,0,stream>>>((A),(Bt),(bias),nullptr,nullptr,(C),(M),(N),(K),(ldc),(relu))

extern "C" void kernel_launch(void* const* d_in, const int* in_sizes, int n_in,
                              void* d_out, int out_size, void* d_ws, size_t ws_size,
                              hipStream_t stream)
{
    const float* rgb_feat   = (const float*)d_in[0];
    const float* ray_diff   = (const float*)d_in[1];
    const int*   maskp      = (const int*)d_in[2];
    const float* pts        = (const float*)d_in[3];
    const float* ray_d      = (const float*)d_in[4];
    const float* rgbfeat_w1 = (const float*)d_in[5];
    const float* rgbfeat_b1 = (const float*)d_in[6];
    const float* rgbfeat_w2 = (const float*)d_in[7];
    const float* rgbfeat_b2 = (const float*)d_in[8];
    const float* c_ln_g = (const float*)d_in[9];
    const float* c_ln_b = (const float*)d_in[10];
    const float* c_qw   = (const float*)d_in[11];
    const float* c_kw   = (const float*)d_in[12];
    const float* c_vw   = (const float*)d_in[13];
    const float* c_pw1  = (const float*)d_in[14];
    const float* c_pb1  = (const float*)d_in[15];
    const float* c_pw2  = (const float*)d_in[16];
    const float* c_pb2  = (const float*)d_in[17];
    const float* c_aw1  = (const float*)d_in[18];
    const float* c_ab1  = (const float*)d_in[19];
    const float* c_aw2  = (const float*)d_in[20];
    const float* c_ab2  = (const float*)d_in[21];
    const float* c_ow   = (const float*)d_in[22];
    const float* c_ob   = (const float*)d_in[23];
    const float* c_fg   = (const float*)d_in[24];
    const float* c_fb   = (const float*)d_in[25];
    const float* c_fw1  = (const float*)d_in[26];
    const float* c_fb1  = (const float*)d_in[27];
    const float* c_fw2  = (const float*)d_in[28];
    const float* c_fb2  = (const float*)d_in[29];
    const float* s_ln_g = (const float*)d_in[30];
    const float* s_ln_b = (const float*)d_in[31];
    const float* s_qw   = (const float*)d_in[32];
    const float* s_kw   = (const float*)d_in[33];
    const float* s_vw   = (const float*)d_in[34];
    const float* s_ow   = (const float*)d_in[35];
    const float* s_ob   = (const float*)d_in[36];
    const float* s_fg   = (const float*)d_in[37];
    const float* s_fb   = (const float*)d_in[38];
    const float* s_fw1  = (const float*)d_in[39];
    const float* s_fb1  = (const float*)d_in[40];
    const float* s_fw2  = (const float*)d_in[41];
    const float* s_fb2  = (const float*)d_in[42];
    const float* q_w1   = (const float*)d_in[43];
    const float* q_b1   = (const float*)d_in[44];
    const float* q_w2   = (const float*)d_in[45];
    const float* q_b2   = (const float*)d_in[46];
    const float* norm_g = (const float*)d_in[47];
    const float* norm_b = (const float*)d_in[48];
    const float* out_w  = (const float*)d_in[49];
    const float* out_b  = (const float*)d_in[50];
    float* out = (float*)d_out;

    // ---- workspace carve (256B aligned) ----
    char* p = (char*)d_ws;
    auto alloc = [&](size_t bytes) { char* r = p; p += (bytes + 255) & ~(size_t)255; return r; };
    short* rgbf  = (short*)alloc((size_t)BSV * 256 * 2);
    short* hall  = (short*)alloc((size_t)DD * BSV * 32 * 2);
    short* a_in  = (short*)alloc((size_t)BSV * 256 * 2);
    short* obb   = (short*)alloc((size_t)BS * 256 * 2);
    short* xq    = (short*)alloc((size_t)BS * 256 * 2);
    short* hb    = (short*)alloc((size_t)BS * 256 * 2);
    short* catb  = (short*)alloc((size_t)BS * 384 * 2);
    short* qkv   = (short*)alloc((size_t)BS * 768 * 2);
    short* rgbp  = qkv;
    float* qf    = (float*)alloc((size_t)BS * 256 * 4);
    float* fq    = (float*)alloc((size_t)BS * 256 * 4);
    // weights
    short* w1T   = (short*)alloc(256 * 64 * 2);
    short* w2T   = (short*)alloc(256 * 256 * 2);
    short* qwT   = (short*)alloc((size_t)DD * 256 * 256 * 2);
    short* kvpT  = (short*)alloc((size_t)DD * 512 * 288 * 2);
    short* aw1T  = (short*)alloc((size_t)DD * 32 * 256 * 2);
    short* aw2T  = (short*)alloc((size_t)DD * 256 * 32 * 2);
    short* owT   = (short*)alloc((size_t)DD * 256 * 256 * 2);
    short* fw1T  = (short*)alloc((size_t)DD * 1024 * 256 * 2);
    short* fw2T  = (short*)alloc((size_t)DD * 256 * 1024 * 2);
    short* sqkvT = (short*)alloc((size_t)DD * 768 * 256 * 2);
    short* sowT  = (short*)alloc((size_t)DD * 256 * 256 * 2);
    short* sfw1T = (short*)alloc((size_t)DD * 1024 * 256 * 2);
    short* sfw2T = (short*)alloc((size_t)DD * 256 * 1024 * 2);
    short* qw1T  = (short*)alloc((size_t)4 * 256 * 384 * 2);
    short* qw2T  = (short*)alloc((size_t)4 * 256 * 256 * 2);

    // ---- batched weight conversion (one dispatch) ----
    WJobs wj; int nj = 0, totblk = 0;
    // frag=0 (row-major [N,Kpad]), frag=1 (fragment-packed; KS/ntoff/ksoff)
    auto addj = [&](const float* s, short* d, int K, int N, int frag,
                    int KS, int ntoff, int ksoff, int Kpad,
                    int zi, size_t zo, int nz) {
        WJob& J = wj.j[nj++];
        J.src = s; J.dst = d; J.K = K; J.N = N; J.frag = frag;
        J.KS = KS; J.ntoff = ntoff; J.ksoff = ksoff; J.Kpad = Kpad;
        J.zi = zi; J.zo = zo; J.gy = (K + 31) >> 5;
        J.nblk = (N >> 5) * J.gy * nz;
        totblk += J.nblk;
    };
    addj(rgbfeat_w1, w1T, 35, 256, 0, 0, 0, 0, 64, 0, 0, 1);
    addj(rgbfeat_w2, w2T, 256, 256, 0, 0, 0, 0, 256, 0, 0, 1);
    addj(c_qw,  qwT,  256, 256, 1, 8, 0, 0, 0, 65536, 65536, DD);
    addj(c_kw,  kvpT, 256, 256, 1, 9, 0, 0, 0, 65536, 147456, DD);
    addj(c_pw2, kvpT, 32, 256, 1, 9, 0, 8, 0, 8192, 147456, DD);
    addj(c_vw,  kvpT, 256, 256, 1, 9, 16, 0, 0, 65536, 147456, DD);
    addj(c_pw2, kvpT, 32, 256, 1, 9, 16, 8, 0, 8192, 147456, DD);
    addj(c_aw1, aw1T, 256, 32, 1, 8, 0, 0, 0, 8192, 8192, DD);
    addj(c_aw2, aw2T, 32, 256, 1, 1, 0, 0, 0, 8192, 8192, DD);
    addj(c_ow,  owT,  256, 256, 1, 8, 0, 0, 0, 65536, 65536, DD);
    addj(c_fw1, fw1T, 256, 1024, 1, 8, 0, 0, 0, 262144, 262144, DD);
    addj(c_fw2, fw2T, 1024, 256, 1, 32, 0, 0, 0, 262144, 262144, DD);
    addj(s_qw,  sqkvT, 256, 256, 1, 8, 0, 0, 0, 65536, 196608, DD);
    addj(s_kw,  sqkvT, 256, 256, 1, 8, 16, 0, 0, 65536, 196608, DD);
    addj(s_vw,  sqkvT, 256, 256, 1, 8, 32, 0, 0, 65536, 196608, DD);
    addj(s_ow,  sowT,  256, 256, 1, 8, 0, 0, 0, 65536, 65536, DD);
    addj(s_fw1, sfw1T, 256, 1024, 1, 8, 0, 0, 0, 262144, 262144, DD);
    addj(s_fw2, sfw2T, 1024, 256, 1, 32, 0, 0, 0, 262144, 262144, DD);
    addj(q_w1,  qw1T, 346, 256, 1, 12, 0, 0, 0, 88576, 98304, 4);
    addj(q_w2,  qw2T, 256, 256, 1, 8, 0, 0, 0, 65536, 65536, 4);
    wconv_all<<<totblk, dim3(32, 8), 0, stream>>>(wj);

    // ---- preamble ----
    catpenc<<<(BS * 128) / 256, 256, 0, stream>>>(pts, ray_d, catb);
    rgbhall<<<(BSV * 64 + DD * BSV * 32) / 256, 256, 0, stream>>>(
        rgb_feat, ray_diff, c_pw1, c_pb1, rgbp, hall);
    GEMM_BF(128, 128, 64, 64, rgbp, w1T, rgbfeat_b1, a_in, BSV, 256, 64, 256, 1);
    GEMM_BF(128, 128, 64, 64, a_in, w2T, rgbfeat_b2, rgbf, BSV, 256, 256, 256, 0);
    vmaxln<<<BS, 256, 0, stream>>>(rgbf, c_ln_g, c_ln_b, fq, xq);
    qgemm0<<<256, 256, 0, stream>>>(xq, qwT, qf);

    for (int i = 0; i < DD; i++) {
        int j = i >> 1;
        crosskv<<<BSV / 64, 512, 0, stream>>>(
            rgbf, hall + (size_t)i * BSV * 32, kvpT + (size_t)i * 147456,
            qf, maskp,
            aw1T + (size_t)i * 8192, c_ab1 + i * 32,
            aw2T + (size_t)i * 8192, c_ab2 + i * 256, obb);
        chainA<<<256, 512, 0, stream>>>(obb, fq, catb, qkv,
            owT + (size_t)i * 65536, c_ob + i * 256, c_fg + i * 256, c_fb + i * 256,
            fw1T + (size_t)i * 262144, c_fb1 + i * 1024,
            fw2T + (size_t)i * 262144, c_fb2 + i * 256,
            qw1T + (size_t)j * 98304, q_b1 + j * 256,
            qw2T + (size_t)j * 65536, q_b2 + j * 256,
            s_ln_g + i * 256, s_ln_b + i * 256,
            sqkvT + (size_t)i * 196608, !(i & 1));
        attn_mfma<<<BB * 4, 256, 0, stream>>>(qkv, obb);
        int last = (i == DD - 1);
        chainB<<<256, 512, 0, stream>>>(obb, fq,
            sowT + (size_t)i * 65536, s_ob + i * 256, s_fg + i * 256, s_fb + i * 256,
            sfw1T + (size_t)i * 262144, s_fb1 + i * 1024,
            sfw2T + (size_t)i * 262144, s_fb2 + i * 256,
            last ? norm_g : c_ln_g + (i + 1) * 256,
            last ? norm_b : c_ln_b + (i + 1) * 256,
            last ? 1e-5f : 1e-6f,
            last ? nullptr : qwT + (size_t)(i + 1) * 65536,
            qf, last ? hb : nullptr);
    }

    headk<<<BB, 256, 0, stream>>>(hb, out_w, out_b, out);
}